// Round 1
// baseline (401.076 us; speedup 1.0000x reference)
//
#include <hip/hip_runtime.h>
#include <stdint.h>

#define NTOK 32768
#define BD   512
#define NB   16
#define LYK  256
#define IMGD 768

typedef __attribute__((ext_vector_type(4))) float f32x4;
typedef __attribute__((ext_vector_type(8))) short s16x8;
typedef unsigned short u16;

__device__ __forceinline__ float bf2f(u16 u) {
  union { uint32_t i; float f; } v; v.i = ((uint32_t)u) << 16; return v.f;
}
__device__ __forceinline__ u16 f2bf(float f) {
  union { float f; uint32_t i; } v; v.f = f;
  uint32_t r = v.i + 0x7fffu + ((v.i >> 16) & 1u);
  return (u16)(r >> 16);
}
__device__ __forceinline__ void gl_lds16(const u16* g, u16* l) {
  __builtin_amdgcn_global_load_lds(
      (const __attribute__((address_space(1))) uint32_t*)g,
      (__attribute__((address_space(3))) uint32_t*)l, 16, 0, 0);
}
__device__ __forceinline__ f32x4 mfma16(s16x8 a, s16x8 b, f32x4 c) {
  return __builtin_amdgcn_mfma_f32_16x16x32_bf16(a, b, c, 0, 0, 0);
}

// ---------------- fp32 -> bf16 convert (weights, y) ----------------
__global__ __launch_bounds__(256) void cvt_f32_bf16(const float* __restrict__ s,
                                                    u16* __restrict__ d, int n) {
  int i = (blockIdx.x * 256 + threadIdx.x) * 8;
  if (i >= n) return;
  f32x4 a = *(const f32x4*)(s + i);
  f32x4 b = *(const f32x4*)(s + i + 4);
  s16x8 o;
#pragma unroll
  for (int j = 0; j < 4; ++j) { o[j] = (short)f2bf(a[j]); o[4 + j] = (short)f2bf(b[j]); }
  *(s16x8*)(d + i) = o;
}

// ---------------- batch offsets via binary search ----------------
__global__ void calc_off(const int* __restrict__ bids, int* __restrict__ off) {
  int b = threadIdx.x;
  if (b > NB) return;
  int lo = 0, hi = NTOK;
  while (lo < hi) { int mid = (lo + hi) >> 1; if (bids[mid] < b) lo = mid + 1; else hi = mid; }
  off[b] = lo;
}

// ---------------- LayerNorm: fp32 in -> bf16 out (one row per wave) -------
__global__ __launch_bounds__(256) void ln_f32_bf16(const float* __restrict__ X,
                                                   const float* __restrict__ g,
                                                   const float* __restrict__ be,
                                                   u16* __restrict__ out) {
  const int lane = threadIdx.x & 63;
  const size_t row = (size_t)blockIdx.x * 4 + (threadIdx.x >> 6);
  const float* x = X + row * BD + lane * 8;
  f32x4 a = *(const f32x4*)x;
  f32x4 b = *(const f32x4*)(x + 4);
  float v[8] = {a[0], a[1], a[2], a[3], b[0], b[1], b[2], b[3]};
  float s = 0.f, s2 = 0.f;
#pragma unroll
  for (int j = 0; j < 8; ++j) { s += v[j]; s2 += v[j] * v[j]; }
#pragma unroll
  for (int m = 1; m < 64; m <<= 1) { s += __shfl_xor(s, m); s2 += __shfl_xor(s2, m); }
  float mean = s * (1.f / BD);
  float rstd = rsqrtf(s2 * (1.f / BD) - mean * mean + 1e-5f);
  const float* gp = g + lane * 8;
  const float* bp = be + lane * 8;
  s16x8 o;
#pragma unroll
  for (int j = 0; j < 8; ++j) o[j] = (short)f2bf((v[j] - mean) * rstd * gp[j] + bp[j]);
  *(s16x8*)(out + row * BD + lane * 8) = o;
}

// ---------------- LayerNorm: bf16 in -> fp32 out ----------------
__global__ __launch_bounds__(256) void ln_bf16_f32(const u16* __restrict__ Z,
                                                   const float* __restrict__ g,
                                                   const float* __restrict__ be,
                                                   float* __restrict__ out) {
  const int lane = threadIdx.x & 63;
  const size_t row = (size_t)blockIdx.x * 4 + (threadIdx.x >> 6);
  s16x8 zv = *(const s16x8*)(Z + row * BD + lane * 8);
  float v[8];
#pragma unroll
  for (int j = 0; j < 8; ++j) v[j] = bf2f((u16)zv[j]);
  float s = 0.f, s2 = 0.f;
#pragma unroll
  for (int j = 0; j < 8; ++j) { s += v[j]; s2 += v[j] * v[j]; }
#pragma unroll
  for (int m = 1; m < 64; m <<= 1) { s += __shfl_xor(s, m); s2 += __shfl_xor(s2, m); }
  float mean = s * (1.f / BD);
  float rstd = rsqrtf(s2 * (1.f / BD) - mean * mean + 1e-5f);
  const float* gp = g + lane * 8;
  const float* bp = be + lane * 8;
  f32x4 o0, o1;
#pragma unroll
  for (int j = 0; j < 4; ++j) o0[j] = (v[j] - mean) * rstd * gp[j] + bp[j];
#pragma unroll
  for (int j = 0; j < 4; ++j) o1[j] = (v[4 + j] - mean) * rstd * gp[4 + j] + bp[4 + j];
  float* op = out + row * BD + lane * 8;
  *(f32x4*)op = o0;
  *(f32x4*)(op + 4) = o1;
}

// ---------------- NT GEMM: C[M,512] = A[M,K] @ W[512,K]^T + bias ----------
// EPI 0: bf16 out; 1: gelu+bf16 out; 2: +resid (bf16) -> bf16 out
template <int EPI>
__global__ __launch_bounds__(256, 2) void gemm_nt(const u16* __restrict__ A,
                                                  const u16* __restrict__ W,
                                                  const float* __restrict__ bias,
                                                  u16* __restrict__ C,
                                                  const u16* __restrict__ resid, int K) {
  __shared__ u16 As[128 * 32];
  __shared__ u16 Bs[128 * 32];
  const int tid = threadIdx.x;
  const int wave = tid >> 6, lane = tid & 63;
  const int wm = (wave & 1) * 64, wn = (wave >> 1) * 64;
  const int quad = lane >> 4, l16 = lane & 15;
  const int m0 = blockIdx.x * 128, n0 = blockIdx.y * 128;

  f32x4 acc[4][4];
#pragma unroll
  for (int i = 0; i < 4; ++i)
#pragma unroll
    for (int j = 0; j < 4; ++j) acc[i][j] = f32x4{0.f, 0.f, 0.f, 0.f};

  const int srow = wave * 32 + (lane >> 2);
  const int scol = (lane & 3) * 8;
  const u16* gA0 = A + (size_t)(m0 + srow) * K + scol;
  const u16* gA1 = gA0 + (size_t)16 * K;
  const u16* gW0 = W + (size_t)(n0 + srow) * K + scol;
  const u16* gW1 = gW0 + (size_t)16 * K;
  u16* lA = As + wave * 1024;  // wave-uniform LDS base; HW adds lane*16B
  u16* lB = Bs + wave * 1024;

  for (int k0 = 0; k0 < K; k0 += 32) {
    __syncthreads();
    gl_lds16(gA0 + k0, lA);
    gl_lds16(gA1 + k0, lA + 512);
    gl_lds16(gW0 + k0, lB);
    gl_lds16(gW1 + k0, lB + 512);
    __syncthreads();
    s16x8 af[4], bfr[4];
#pragma unroll
    for (int mt = 0; mt < 4; ++mt)
      af[mt] = *(const s16x8*)&As[(wm + mt * 16 + l16) * 32 + quad * 8];
#pragma unroll
    for (int nt = 0; nt < 4; ++nt)
      bfr[nt] = *(const s16x8*)&Bs[(wn + nt * 16 + l16) * 32 + quad * 8];
#pragma unroll
    for (int mt = 0; mt < 4; ++mt)
#pragma unroll
      for (int nt = 0; nt < 4; ++nt)
        acc[mt][nt] = mfma16(af[mt], bfr[nt], acc[mt][nt]);
  }

#pragma unroll
  for (int nt = 0; nt < 4; ++nt) {
    const int n = n0 + wn + nt * 16 + l16;
    const float bia = bias[n];
#pragma unroll
    for (int mt = 0; mt < 4; ++mt) {
      const int mb = m0 + wm + mt * 16 + quad * 4;
#pragma unroll
      for (int r = 0; r < 4; ++r) {
        float v = acc[mt][nt][r] + bia;
        size_t idx = (size_t)(mb + r) * BD + n;
        if (EPI == 1) v = 0.5f * v * (1.f + erff(v * 0.70710678118654752f));
        if (EPI == 2) v += bf2f(resid[idx]);
        C[idx] = f2bf(v);
      }
    }
  }
}

// ---------------- attention: per (qtile64, head, batch) -------------------
__global__ __launch_bounds__(256, 2) void attn_k(const u16* __restrict__ Q,
                                                 const u16* __restrict__ Kg,
                                                 const u16* __restrict__ Vg,
                                                 const int* __restrict__ off,
                                                 u16* __restrict__ O) {
  const int t = blockIdx.x, h = blockIdx.y, b = blockIdx.z;
  const int qend = off[b + 1];
  const int qstart = off[b] + t * 64;
  if (qstart >= qend) return;

  // K tile [256][64] stride 88 (16B-aligned rows, 2-way-free banks); later reused for P
  __shared__ u16 KP[256 * 88];
  // V^T tile [64][256] stride 264
  __shared__ u16 Vt[64 * 264];

  const int tid = threadIdx.x;
  const int wave = tid >> 6, lane = tid & 63;
  const int quad = lane >> 4, l16 = lane & 15;

  {  // load K_h
    const u16* src = Kg + ((size_t)b * LYK) * BD + h * 64;
#pragma unroll
    for (int s = 0; s < 8; ++s) {
      int seg = tid + s * 256;           // 0..2047
      int l = seg >> 3, c8 = (seg & 7) * 8;
      *(s16x8*)&KP[l * 88 + c8] = *(const s16x8*)&src[(size_t)l * BD + c8];
    }
  }
  {  // load V_h transposed
    const u16* src = Vg + ((size_t)b * LYK) * BD + h * 64;
    int d = tid & 63, lg = tid >> 6;
    for (int l = lg * 64; l < lg * 64 + 64; ++l)
      Vt[d * 264 + l] = src[(size_t)l * BD + d];
  }
  // Q fragments (A-layout: m=lane&15, k=quad*8+j), direct from global
  int qrow = qstart + wave * 16 + l16;
  if (qrow > NTOK - 1) qrow = NTOK - 1;
  const u16* qp = Q + (size_t)qrow * BD + h * 64 + quad * 8;
  s16x8 aq0 = *(const s16x8*)qp;
  s16x8 aq1 = *(const s16x8*)(qp + 32);

  __syncthreads();

  // S = Q K^T : 16 key-tiles of 16, K-dim 64 (2 mfma steps)
  f32x4 sacc[16];
#pragma unroll
  for (int nt = 0; nt < 16; ++nt) sacc[nt] = f32x4{0.f, 0.f, 0.f, 0.f};
#pragma unroll
  for (int nt = 0; nt < 16; ++nt) {
    const u16* kp = &KP[(nt * 16 + l16) * 88 + quad * 8];
    s16x8 b0 = *(const s16x8*)kp;
    s16x8 b1 = *(const s16x8*)(kp + 32);
    sacc[nt] = mfma16(aq0, b0, sacc[nt]);
    sacc[nt] = mfma16(aq1, b1, sacc[nt]);
  }

  // softmax over 256 keys; row (quad*4+r) lives in this quad's 16 lanes
  float inv[4];
#pragma unroll
  for (int r = 0; r < 4; ++r) {
    float m = -1e30f;
#pragma unroll
    for (int nt = 0; nt < 16; ++nt) m = fmaxf(m, sacc[nt][r]);
#pragma unroll
    for (int msk = 1; msk < 16; msk <<= 1) m = fmaxf(m, __shfl_xor(m, msk));
    float sum = 0.f;
#pragma unroll
    for (int nt = 0; nt < 16; ++nt) {
      float p = __expf(0.125f * (sacc[nt][r] - m));  // dh^-0.5 = 0.125
      sacc[nt][r] = p;
      sum += p;
    }
#pragma unroll
    for (int msk = 1; msk < 16; msk <<= 1) sum += __shfl_xor(sum, msk);
    inv[r] = 1.f / sum;
  }

  __syncthreads();  // all waves done reading K before P overwrites it

  // write normalized P (bf16) into per-wave region of KP, rows stride 264
  u16* Pw = KP + wave * (16 * 264);
#pragma unroll
  for (int nt = 0; nt < 16; ++nt)
#pragma unroll
    for (int r = 0; r < 4; ++r)
      Pw[(quad * 4 + r) * 264 + nt * 16 + l16] = f2bf(sacc[nt][r] * inv[r]);

  // O = P V : M=16, N=64, K=256
  f32x4 oacc[4];
#pragma unroll
  for (int n2 = 0; n2 < 4; ++n2) oacc[n2] = f32x4{0.f, 0.f, 0.f, 0.f};
#pragma unroll
  for (int kc = 0; kc < 8; ++kc) {
    s16x8 ap = *(const s16x8*)&Pw[l16 * 264 + kc * 32 + quad * 8];
#pragma unroll
    for (int n2 = 0; n2 < 4; ++n2) {
      s16x8 bv = *(const s16x8*)&Vt[(n2 * 16 + l16) * 264 + kc * 32 + quad * 8];
      oacc[n2] = mfma16(ap, bv, oacc[n2]);
    }
  }

#pragma unroll
  for (int n2 = 0; n2 < 4; ++n2)
#pragma unroll
    for (int r = 0; r < 4; ++r) {
      int q = qstart + wave * 16 + quad * 4 + r;
      if (q < qend)
        O[(size_t)q * BD + h * 64 + n2 * 16 + l16] = f2bf(oacc[n2][r]);
    }
}

extern "C" void kernel_launch(void* const* d_in, const int* in_sizes, int n_in,
                              void* d_out, int out_size, void* d_ws, size_t ws_size,
                              hipStream_t stream) {
  const float* F    = (const float*)d_in[0];
  const float* yIn  = (const float*)d_in[1];
  const float* ln_g = (const float*)d_in[2];
  const float* ln_b = (const float*)d_in[3];
  const float* Wq   = (const float*)d_in[4];
  const float* Wk   = (const float*)d_in[5];
  const float* Wv   = (const float*)d_in[6];
  const float* bq   = (const float*)d_in[7];
  const float* bk   = (const float*)d_in[8];
  const float* bv   = (const float*)d_in[9];
  const float* Wo   = (const float*)d_in[10];
  const float* bo   = (const float*)d_in[11];
  const float* W1   = (const float*)d_in[12];
  const float* b1   = (const float*)d_in[13];
  const float* W2   = (const float*)d_in[14];
  const float* b2   = (const float*)d_in[15];
  const int* bids   = (const int*)d_in[16];

  char* ws = (char*)d_ws;
  size_t cur = 0;
  auto alloc = [&](size_t bytes) {
    void* p = ws + cur;
    cur += (bytes + 255) & ~(size_t)255;
    return p;
  };

  int* off  = (int*)alloc(68);
  u16* wq_b = (u16*)alloc((size_t)262144 * 2);
  u16* wk_b = (u16*)alloc((size_t)262144 * 2);
  u16* wv_b = (u16*)alloc((size_t)262144 * 2);
  u16* wo_b = (u16*)alloc((size_t)262144 * 2);
  u16* w2_b = (u16*)alloc((size_t)262144 * 2);
  u16* w1_b = (u16*)alloc((size_t)393216 * 2);
  u16* y_b  = (u16*)alloc((size_t)3145728 * 2);
  u16* U    = (u16*)alloc((size_t)4096 * BD * 2);
  u16* ym   = (u16*)alloc((size_t)4096 * BD * 2);
  u16* Kb   = (u16*)alloc((size_t)4096 * BD * 2);
  u16* Vb   = (u16*)alloc((size_t)4096 * BD * 2);
  u16* xn   = (u16*)alloc((size_t)NTOK * BD * 2);
  u16* Qb   = (u16*)alloc((size_t)NTOK * BD * 2);
  u16* Ob   = (u16*)alloc((size_t)NTOK * BD * 2);
  u16* Zb   = (u16*)alloc((size_t)NTOK * BD * 2);

  calc_off<<<1, 64, 0, stream>>>(bids, off);
  cvt_f32_bf16<<<262144 / 2048, 256, 0, stream>>>(Wq, wq_b, 262144);
  cvt_f32_bf16<<<262144 / 2048, 256, 0, stream>>>(Wk, wk_b, 262144);
  cvt_f32_bf16<<<262144 / 2048, 256, 0, stream>>>(Wv, wv_b, 262144);
  cvt_f32_bf16<<<262144 / 2048, 256, 0, stream>>>(Wo, wo_b, 262144);
  cvt_f32_bf16<<<262144 / 2048, 256, 0, stream>>>(W2, w2_b, 262144);
  cvt_f32_bf16<<<393216 / 2048, 256, 0, stream>>>(W1, w1_b, 393216);
  cvt_f32_bf16<<<3145728 / 2048, 256, 0, stream>>>(yIn, y_b, 3145728);
  ln_f32_bf16<<<NTOK / 4, 256, 0, stream>>>(F, ln_g, ln_b, xn);

  // image-feature MLP + K/V projections (M = B*LY = 4096)
  gemm_nt<1><<<dim3(32, 4), 256, 0, stream>>>(y_b, w1_b, b1, U, nullptr, IMGD);
  gemm_nt<0><<<dim3(32, 4), 256, 0, stream>>>(U, w2_b, b2, ym, nullptr, BD);
  gemm_nt<0><<<dim3(32, 4), 256, 0, stream>>>(ym, wk_b, bk, Kb, nullptr, BD);
  gemm_nt<0><<<dim3(32, 4), 256, 0, stream>>>(ym, wv_b, bv, Vb, nullptr, BD);
  // Q projection (M = 32768)
  gemm_nt<0><<<dim3(256, 4), 256, 0, stream>>>(xn, wq_b, bq, Qb, nullptr, BD);
  // cross-attention on real tokens only
  attn_k<<<dim3(40, 8, NB), 256, 0, stream>>>(Qb, Kb, Vb, off, Ob);
  // output projection + residual, then final LN -> fp32 out
  gemm_nt<2><<<dim3(256, 4), 256, 0, stream>>>(Ob, wo_b, bo, Zb, xn, BD);
  ln_bf16_f32<<<NTOK / 4, 256, 0, stream>>>(Zb, ln_g, ln_b, (float*)d_out);
}

// Round 2
// 398.160 us; speedup vs baseline: 1.0073x; 1.0073x over previous
//
#include <hip/hip_runtime.h>
#include <stdint.h>

#define NTOK 32768
#define BD   512
#define NB   16
#define LYK  256
#define IMGD 768

typedef __attribute__((ext_vector_type(4))) float f32x4;
typedef __attribute__((ext_vector_type(8))) short s16x8;
typedef __attribute__((ext_vector_type(4))) unsigned short u16x4;
typedef unsigned short u16;

__device__ __forceinline__ float bf2f(u16 u) {
  union { uint32_t i; float f; } v; v.i = ((uint32_t)u) << 16; return v.f;
}
__device__ __forceinline__ u16 f2bf(float f) {
  union { float f; uint32_t i; } v; v.f = f;
  uint32_t r = v.i + 0x7fffu + ((v.i >> 16) & 1u);
  return (u16)(r >> 16);
}
__device__ __forceinline__ void gl_lds16(const u16* g, u16* l) {
  __builtin_amdgcn_global_load_lds(
      (const __attribute__((address_space(1))) uint32_t*)g,
      (__attribute__((address_space(3))) uint32_t*)l, 16, 0, 0);
}
__device__ __forceinline__ f32x4 mfma16(s16x8 a, s16x8 b, f32x4 c) {
  return __builtin_amdgcn_mfma_f32_16x16x32_bf16(a, b, c, 0, 0, 0);
}

// ---------------- one fused fp32 -> bf16 convert for all weights + y ------
__global__ __launch_bounds__(256) void cvt_all(
    const float* __restrict__ wq, const float* __restrict__ wk,
    const float* __restrict__ wv, const float* __restrict__ wo,
    const float* __restrict__ w2, const float* __restrict__ w1,
    const float* __restrict__ y,
    u16* __restrict__ dq, u16* __restrict__ dkv, u16* __restrict__ dwo,
    u16* __restrict__ dw2, u16* __restrict__ dw1, u16* __restrict__ dy) {
  int bid = blockIdx.x;
  const float* s; u16* d; int base;
  if      (bid < 128)  { s = wq; d = dq;            base = 0;   }
  else if (bid < 256)  { s = wk; d = dkv;           base = 128; }
  else if (bid < 384)  { s = wv; d = dkv + 262144;  base = 256; }
  else if (bid < 512)  { s = wo; d = dwo;           base = 384; }
  else if (bid < 640)  { s = w2; d = dw2;           base = 512; }
  else if (bid < 832)  { s = w1; d = dw1;           base = 640; }
  else                 { s = y;  d = dy;            base = 832; }
  int i = ((bid - base) * 256 + threadIdx.x) * 8;
  f32x4 a = *(const f32x4*)(s + i);
  f32x4 b = *(const f32x4*)(s + i + 4);
  s16x8 o;
#pragma unroll
  for (int j = 0; j < 4; ++j) { o[j] = (short)f2bf(a[j]); o[4 + j] = (short)f2bf(b[j]); }
  *(s16x8*)(d + i) = o;
}

// ---------------- batch offsets via binary search ----------------
__global__ void calc_off(const int* __restrict__ bids, int* __restrict__ off) {
  int b = threadIdx.x;
  if (b > NB) return;
  int lo = 0, hi = NTOK;
  while (lo < hi) { int mid = (lo + hi) >> 1; if (bids[mid] < b) lo = mid + 1; else hi = mid; }
  off[b] = lo;
}

// ---------------- LayerNorm: fp32 in -> bf16 out (one row per wave) -------
__global__ __launch_bounds__(256) void ln_f32_bf16(const float* __restrict__ X,
                                                   const float* __restrict__ g,
                                                   const float* __restrict__ be,
                                                   u16* __restrict__ out) {
  const int lane = threadIdx.x & 63;
  const size_t row = (size_t)blockIdx.x * 4 + (threadIdx.x >> 6);
  const float* x = X + row * BD + lane * 8;
  f32x4 a = *(const f32x4*)x;
  f32x4 b = *(const f32x4*)(x + 4);
  float v[8] = {a[0], a[1], a[2], a[3], b[0], b[1], b[2], b[3]};
  float s = 0.f, s2 = 0.f;
#pragma unroll
  for (int j = 0; j < 8; ++j) { s += v[j]; s2 += v[j] * v[j]; }
#pragma unroll
  for (int m = 1; m < 64; m <<= 1) { s += __shfl_xor(s, m); s2 += __shfl_xor(s2, m); }
  float mean = s * (1.f / BD);
  float rstd = rsqrtf(s2 * (1.f / BD) - mean * mean + 1e-5f);
  const float* gp = g + lane * 8;
  const float* bp = be + lane * 8;
  s16x8 o;
#pragma unroll
  for (int j = 0; j < 8; ++j) o[j] = (short)f2bf((v[j] - mean) * rstd * gp[j] + bp[j]);
  *(s16x8*)(out + row * BD + lane * 8) = o;
}

// ---------------- LayerNorm: bf16 in -> fp32 out ----------------
__global__ __launch_bounds__(256) void ln_bf16_f32(const u16* __restrict__ Z,
                                                   const float* __restrict__ g,
                                                   const float* __restrict__ be,
                                                   float* __restrict__ out) {
  const int lane = threadIdx.x & 63;
  const size_t row = (size_t)blockIdx.x * 4 + (threadIdx.x >> 6);
  s16x8 zv = *(const s16x8*)(Z + row * BD + lane * 8);
  float v[8];
#pragma unroll
  for (int j = 0; j < 8; ++j) v[j] = bf2f((u16)zv[j]);
  float s = 0.f, s2 = 0.f;
#pragma unroll
  for (int j = 0; j < 8; ++j) { s += v[j]; s2 += v[j] * v[j]; }
#pragma unroll
  for (int m = 1; m < 64; m <<= 1) { s += __shfl_xor(s, m); s2 += __shfl_xor(s2, m); }
  float mean = s * (1.f / BD);
  float rstd = rsqrtf(s2 * (1.f / BD) - mean * mean + 1e-5f);
  const float* gp = g + lane * 8;
  const float* bp = be + lane * 8;
  f32x4 o0, o1;
#pragma unroll
  for (int j = 0; j < 4; ++j) o0[j] = (v[j] - mean) * rstd * gp[j] + bp[j];
#pragma unroll
  for (int j = 0; j < 4; ++j) o1[j] = (v[4 + j] - mean) * rstd * gp[4 + j] + bp[4 + j];
  float* op = out + row * BD + lane * 8;
  *(f32x4*)op = o0;
  *(f32x4*)(op + 4) = o1;
}

// ---------------- NT GEMM: C[M,TN-wide] = A[M,K] @ W[N,K]^T + bias --------
// TM: 128 (wave 64x64 quadrant) or 64 (wave 64x32 strip). N always 128/block.
// EPI 0: bf16 out; 1: gelu+bf16; 2: +resid bf16; 3: dual K/V out, V transposed
template <int TM, int EPI>
__global__ __launch_bounds__(256, 2) void gemm_nt(const u16* __restrict__ A,
                                                  const u16* __restrict__ W,
                                                  const float* __restrict__ bias,
                                                  u16* __restrict__ C,
                                                  const u16* __restrict__ resid,
                                                  u16* __restrict__ C2,
                                                  const float* __restrict__ bias2,
                                                  int K) {
  constexpr int MT = 4;
  constexpr int NT = (TM == 128) ? 4 : 2;
  __shared__ u16 As[TM * 32];
  __shared__ u16 Bs[128 * 32];
  const int tid = threadIdx.x;
  const int wave = tid >> 6, lane = tid & 63;
  const int wm = (TM == 128) ? (wave & 1) * 64 : 0;
  const int wn = (TM == 128) ? (wave >> 1) * 64 : wave * 32;
  const int quad = lane >> 4, l16 = lane & 15;
  const int m0 = blockIdx.x * TM, n0 = blockIdx.y * 128;

  f32x4 acc[MT][NT];
#pragma unroll
  for (int i = 0; i < MT; ++i)
#pragma unroll
    for (int j = 0; j < NT; ++j) acc[i][j] = f32x4{0.f, 0.f, 0.f, 0.f};

  const int scol = (lane & 3) * 8;
  const int srowA = (TM == 128) ? wave * 32 + (lane >> 2) : wave * 16 + (lane >> 2);
  const int srowB = wave * 32 + (lane >> 2);
  const u16* gA0 = A + (size_t)(m0 + srowA) * K + scol;
  const u16* gA1 = gA0 + (size_t)16 * K;   // only used when TM==128
  const u16* gW0 = W + (size_t)(n0 + srowB) * K + scol;
  const u16* gW1 = gW0 + (size_t)16 * K;
  u16* lA = As + ((TM == 128) ? wave * 1024 : wave * 512);
  u16* lB = Bs + wave * 1024;

  for (int k0 = 0; k0 < K; k0 += 32) {
    __syncthreads();
    gl_lds16(gA0 + k0, lA);
    if (TM == 128) gl_lds16(gA1 + k0, lA + 512);
    gl_lds16(gW0 + k0, lB);
    gl_lds16(gW1 + k0, lB + 512);
    __syncthreads();
    s16x8 af[MT], bfr[NT];
#pragma unroll
    for (int mt = 0; mt < MT; ++mt)
      af[mt] = *(const s16x8*)&As[(wm + mt * 16 + l16) * 32 + quad * 8];
#pragma unroll
    for (int nt = 0; nt < NT; ++nt)
      bfr[nt] = *(const s16x8*)&Bs[(wn + nt * 16 + l16) * 32 + quad * 8];
#pragma unroll
    for (int mt = 0; mt < MT; ++mt)
#pragma unroll
      for (int nt = 0; nt < NT; ++nt)
        acc[mt][nt] = mfma16(af[mt], bfr[nt], acc[mt][nt]);
  }

#pragma unroll
  for (int nt = 0; nt < NT; ++nt) {
    const int n = n0 + wn + nt * 16 + l16;
    const float bia = (EPI == 3) ? (n < BD ? bias[n] : bias2[n - BD]) : bias[n];
#pragma unroll
    for (int mt = 0; mt < MT; ++mt) {
      const int mb = m0 + wm + mt * 16 + quad * 4;
      if (EPI == 3 && n >= BD) {
        // V output, transposed: VT[b][n-512][k] with b = m>>8, k = m&255.
        // r loop spans 4 consecutive k -> one 8B store.
        u16x4 pk;
#pragma unroll
        for (int r = 0; r < 4; ++r) pk[r] = f2bf(acc[mt][nt][r] + bia);
        const int b = mb >> 8, k0i = mb & 255;
        *(u16x4*)&C2[((size_t)b * BD + (n - BD)) * LYK + k0i] = pk;
      } else {
#pragma unroll
        for (int r = 0; r < 4; ++r) {
          float v = acc[mt][nt][r] + bia;
          size_t idx = (size_t)(mb + r) * BD + n;
          if (EPI == 1) v = 0.5f * v * (1.f + erff(v * 0.70710678118654752f));
          if (EPI == 2) v += bf2f(resid[idx]);
          C[idx] = f2bf(v);
        }
      }
    }
  }
}

// ---------------- attention: per (qtile64, head, batch) -------------------
// LDS: K tile [256][72] (36.9KB) shared by 4 waves; after QK^T the same
// buffer holds per-wave P [16][264]. V B-fragments read straight from
// global VT (L2-resident, 4MB). 4 WG/CU.
__global__ __launch_bounds__(256, 4) void attn_k(const u16* __restrict__ Q,
                                                 const u16* __restrict__ Kg,
                                                 const u16* __restrict__ VT,
                                                 const int* __restrict__ off,
                                                 u16* __restrict__ O) {
  const int t = blockIdx.x, h = blockIdx.y, b = blockIdx.z;
  const int qend = off[b + 1];
  const int qstart = off[b] + t * 64;
  if (qstart >= qend) return;

  __shared__ u16 KP[256 * 72];

  const int tid = threadIdx.x;
  const int wave = tid >> 6, lane = tid & 63;
  const int quad = lane >> 4, l16 = lane & 15;

  {  // stage K_h [256][64] -> KP stride 72 (vectorized, 2-way-free banks)
    const u16* src = Kg + ((size_t)b * LYK) * BD + h * 64;
#pragma unroll
    for (int s = 0; s < 8; ++s) {
      int seg = tid + s * 256;       // 0..2047
      int l = seg >> 3, c8 = (seg & 7) * 8;
      *(s16x8*)&KP[l * 72 + c8] = *(const s16x8*)&src[(size_t)l * BD + c8];
    }
  }
  // Q fragments (A-layout: m=lane&15, k=quad*8+j), direct from global
  int qrow = qstart + wave * 16 + l16;
  if (qrow > NTOK - 1) qrow = NTOK - 1;
  const u16* qp = Q + (size_t)qrow * BD + h * 64 + quad * 8;
  s16x8 aq0 = *(const s16x8*)qp;
  s16x8 aq1 = *(const s16x8*)(qp + 32);

  __syncthreads();

  // S = Q K^T : 16 key-tiles of 16, d-dim 64 (2 mfma steps)
  f32x4 sacc[16];
#pragma unroll
  for (int nt = 0; nt < 16; ++nt) sacc[nt] = f32x4{0.f, 0.f, 0.f, 0.f};
#pragma unroll
  for (int nt = 0; nt < 16; ++nt) {
    const u16* kp = &KP[(nt * 16 + l16) * 72 + quad * 8];
    s16x8 b0 = *(const s16x8*)kp;
    s16x8 b1 = *(const s16x8*)(kp + 32);
    sacc[nt] = mfma16(aq0, b0, sacc[nt]);
    sacc[nt] = mfma16(aq1, b1, sacc[nt]);
  }

  // softmax over 256 keys; row (quad*4+r) lives in this quad's 16 lanes.
  // P left unnormalized; 1/sum applied in the epilogue.
  float inv[4];
#pragma unroll
  for (int r = 0; r < 4; ++r) {
    float m = -1e30f;
#pragma unroll
    for (int nt = 0; nt < 16; ++nt) m = fmaxf(m, sacc[nt][r]);
#pragma unroll
    for (int msk = 1; msk < 16; msk <<= 1) m = fmaxf(m, __shfl_xor(m, msk));
    float sum = 0.f;
#pragma unroll
    for (int nt = 0; nt < 16; ++nt) {
      float p = __expf(0.125f * (sacc[nt][r] - m));  // dh^-0.5 = 0.125
      sacc[nt][r] = p;
      sum += p;
    }
#pragma unroll
    for (int msk = 1; msk < 16; msk <<= 1) sum += __shfl_xor(sum, msk);
    inv[r] = 1.f / sum;
  }

  __syncthreads();  // all waves done reading K before P overwrites it

  // per-wave P region [16][264] (bf16, unnormalized)
  u16* Pw = KP + wave * (16 * 264);
#pragma unroll
  for (int nt = 0; nt < 16; ++nt)
#pragma unroll
    for (int r = 0; r < 4; ++r)
      Pw[(quad * 4 + r) * 264 + nt * 16 + l16] = f2bf(sacc[nt][r]);

  // O = P V : M=16, N=64, K=256. B-fragments straight from global VT.
  const u16* vb = VT + ((size_t)b * BD + h * 64) * LYK;
  f32x4 oacc[4];
#pragma unroll
  for (int n2 = 0; n2 < 4; ++n2) oacc[n2] = f32x4{0.f, 0.f, 0.f, 0.f};
#pragma unroll
  for (int kc = 0; kc < 8; ++kc) {
    s16x8 ap = *(const s16x8*)&Pw[l16 * 264 + kc * 32 + quad * 8];
#pragma unroll
    for (int n2 = 0; n2 < 4; ++n2) {
      s16x8 bv = *(const s16x8*)&vb[(size_t)(n2 * 16 + l16) * LYK + kc * 32 + quad * 8];
      oacc[n2] = mfma16(ap, bv, oacc[n2]);
    }
  }

#pragma unroll
  for (int n2 = 0; n2 < 4; ++n2)
#pragma unroll
    for (int r = 0; r < 4; ++r) {
      int q = qstart + wave * 16 + quad * 4 + r;
      if (q < qend)
        O[(size_t)q * BD + h * 64 + n2 * 16 + l16] = f2bf(oacc[n2][r] * inv[r]);
    }
}

extern "C" void kernel_launch(void* const* d_in, const int* in_sizes, int n_in,
                              void* d_out, int out_size, void* d_ws, size_t ws_size,
                              hipStream_t stream) {
  const float* F    = (const float*)d_in[0];
  const float* yIn  = (const float*)d_in[1];
  const float* ln_g = (const float*)d_in[2];
  const float* ln_b = (const float*)d_in[3];
  const float* Wq   = (const float*)d_in[4];
  const float* Wk   = (const float*)d_in[5];
  const float* Wv   = (const float*)d_in[6];
  const float* bq   = (const float*)d_in[7];
  const float* bk   = (const float*)d_in[8];
  const float* bv   = (const float*)d_in[9];
  const float* Wo   = (const float*)d_in[10];
  const float* bo   = (const float*)d_in[11];
  const float* W1   = (const float*)d_in[12];
  const float* b1   = (const float*)d_in[13];
  const float* W2   = (const float*)d_in[14];
  const float* b2   = (const float*)d_in[15];
  const int* bids   = (const int*)d_in[16];

  char* ws = (char*)d_ws;
  size_t cur = 0;
  auto alloc = [&](size_t bytes) {
    void* p = ws + cur;
    cur += (bytes + 255) & ~(size_t)255;
    return p;
  };

  int* off   = (int*)alloc(68);
  u16* wq_b  = (u16*)alloc((size_t)262144 * 2);
  u16* wkv_b = (u16*)alloc((size_t)524288 * 2);   // [Wk; Wv] stacked, 1024x512
  u16* wo_b  = (u16*)alloc((size_t)262144 * 2);
  u16* w2_b  = (u16*)alloc((size_t)262144 * 2);
  u16* w1_b  = (u16*)alloc((size_t)393216 * 2);
  u16* y_b   = (u16*)alloc((size_t)3145728 * 2);
  u16* U     = (u16*)alloc((size_t)4096 * BD * 2);
  u16* ym    = (u16*)alloc((size_t)4096 * BD * 2);
  u16* Kb    = (u16*)alloc((size_t)4096 * BD * 2);
  u16* VT    = (u16*)alloc((size_t)NB * BD * LYK * 2);  // [b][dh_full][key]
  u16* xn    = (u16*)alloc((size_t)NTOK * BD * 2);
  u16* Qb    = (u16*)alloc((size_t)NTOK * BD * 2);
  u16* Ob    = (u16*)alloc((size_t)NTOK * BD * 2);
  u16* Zb    = (u16*)alloc((size_t)NTOK * BD * 2);

  calc_off<<<1, 64, 0, stream>>>(bids, off);
  cvt_all<<<2368, 256, 0, stream>>>(Wq, Wk, Wv, Wo, W2, W1, yIn,
                                    wq_b, wkv_b, wo_b, w2_b, w1_b, y_b);
  ln_f32_bf16<<<NTOK / 4, 256, 0, stream>>>(F, ln_g, ln_b, xn);

  // image-feature MLP (M = 4096); TM=64 tiles -> 256 WGs each
  gemm_nt<64, 1><<<dim3(64, 4), 256, 0, stream>>>(y_b, w1_b, b1, U, nullptr, nullptr, nullptr, IMGD);
  gemm_nt<64, 0><<<dim3(64, 4), 256, 0, stream>>>(U, w2_b, b2, ym, nullptr, nullptr, nullptr, BD);
  // fused K/V projection, N=1024; V written transposed into VT
  gemm_nt<128, 3><<<dim3(32, 8), 256, 0, stream>>>(ym, wkv_b, bk, Kb, nullptr, VT, bv, BD);
  // Q projection (M = 32768)
  gemm_nt<128, 0><<<dim3(256, 4), 256, 0, stream>>>(xn, wq_b, bq, Qb, nullptr, nullptr, nullptr, BD);
  // cross-attention on real tokens only (max count 2248 -> 36 tiles)
  attn_k<<<dim3(36, 8, NB), 256, 0, stream>>>(Qb, Kb, VT, off, Ob);
  // output projection + residual, then final LN -> fp32 out
  gemm_nt<128, 2><<<dim3(256, 4), 256, 0, stream>>>(Ob, wo_b, bo, Zb, xn, nullptr, nullptr, BD);
  ln_bf16_f32<<<NTOK / 4, 256, 0, stream>>>(Zb, ln_g, ln_b, (float*)d_out);
}

// Round 3
// 395.375 us; speedup vs baseline: 1.0144x; 1.0070x over previous
//
#include <hip/hip_runtime.h>
#include <stdint.h>

#define NTOK 32768
#define BD   512
#define NB   16
#define LYK  256
#define IMGD 768

typedef __attribute__((ext_vector_type(4))) float f32x4;
typedef __attribute__((ext_vector_type(8))) short s16x8;
typedef __attribute__((ext_vector_type(4))) unsigned short u16x4;
typedef unsigned short u16;

__device__ __forceinline__ float bf2f(u16 u) {
  union { uint32_t i; float f; } v; v.i = ((uint32_t)u) << 16; return v.f;
}
__device__ __forceinline__ u16 f2bf(float f) {
  union { float f; uint32_t i; } v; v.f = f;
  uint32_t r = v.i + 0x7fffu + ((v.i >> 16) & 1u);
  return (u16)(r >> 16);
}
__device__ __forceinline__ void gl_lds16(const u16* g, u16* l) {
  __builtin_amdgcn_global_load_lds(
      (const __attribute__((address_space(1))) uint32_t*)g,
      (__attribute__((address_space(3))) uint32_t*)l, 16, 0, 0);
}
__device__ __forceinline__ f32x4 mfma16(s16x8 a, s16x8 b, f32x4 c) {
  return __builtin_amdgcn_mfma_f32_16x16x32_bf16(a, b, c, 0, 0, 0);
}

// ---- prep: fused fp32->bf16 converts + LayerNorm(F) + batch offsets ------
// blocks [0,2368): converts; [2368,10560): LN rows; 10560: calc_off
__global__ __launch_bounds__(256) void prep(
    const float* __restrict__ wq, const float* __restrict__ wk,
    const float* __restrict__ wv, const float* __restrict__ wo,
    const float* __restrict__ w2, const float* __restrict__ w1,
    const float* __restrict__ y,  const float* __restrict__ F,
    const float* __restrict__ g,  const float* __restrict__ be,
    const int* __restrict__ bids,
    u16* __restrict__ dq, u16* __restrict__ dkv, u16* __restrict__ dwo,
    u16* __restrict__ dw2, u16* __restrict__ dw1, u16* __restrict__ dy,
    u16* __restrict__ xn, int* __restrict__ off) {
  const int bid = blockIdx.x;
  if (bid < 2368) {
    const float* s; u16* d; int base;
    if      (bid < 128)  { s = wq; d = dq;            base = 0;   }
    else if (bid < 256)  { s = wk; d = dkv;           base = 128; }
    else if (bid < 384)  { s = wv; d = dkv + 262144;  base = 256; }
    else if (bid < 512)  { s = wo; d = dwo;           base = 384; }
    else if (bid < 640)  { s = w2; d = dw2;           base = 512; }
    else if (bid < 832)  { s = w1; d = dw1;           base = 640; }
    else                 { s = y;  d = dy;            base = 832; }
    int i = ((bid - base) * 256 + threadIdx.x) * 8;
    f32x4 a = *(const f32x4*)(s + i);
    f32x4 b = *(const f32x4*)(s + i + 4);
    s16x8 o;
#pragma unroll
    for (int j = 0; j < 4; ++j) { o[j] = (short)f2bf(a[j]); o[4 + j] = (short)f2bf(b[j]); }
    *(s16x8*)(d + i) = o;
  } else if (bid < 10560) {
    const int lane = threadIdx.x & 63;
    const size_t row = (size_t)(bid - 2368) * 4 + (threadIdx.x >> 6);
    const float* x = F + row * BD + lane * 8;
    f32x4 a = *(const f32x4*)x;
    f32x4 b = *(const f32x4*)(x + 4);
    float v[8] = {a[0], a[1], a[2], a[3], b[0], b[1], b[2], b[3]};
    float s = 0.f, s2 = 0.f;
#pragma unroll
    for (int j = 0; j < 8; ++j) { s += v[j]; s2 += v[j] * v[j]; }
#pragma unroll
    for (int m = 1; m < 64; m <<= 1) { s += __shfl_xor(s, m); s2 += __shfl_xor(s2, m); }
    float mean = s * (1.f / BD);
    float rstd = rsqrtf(s2 * (1.f / BD) - mean * mean + 1e-5f);
    const float* gp = g + lane * 8;
    const float* bp = be + lane * 8;
    s16x8 o;
#pragma unroll
    for (int j = 0; j < 8; ++j) o[j] = (short)f2bf((v[j] - mean) * rstd * gp[j] + bp[j]);
    *(s16x8*)(xn + row * BD + lane * 8) = o;
  } else {
    int b = threadIdx.x;
    if (b > NB) return;
    int lo = 0, hi = NTOK;
    while (lo < hi) { int mid = (lo + hi) >> 1; if (bids[mid] < b) lo = mid + 1; else hi = mid; }
    off[b] = lo;
  }
}

// ---------------- LayerNorm: bf16 in -> fp32 out ----------------
__global__ __launch_bounds__(256) void ln_bf16_f32(const u16* __restrict__ Z,
                                                   const float* __restrict__ g,
                                                   const float* __restrict__ be,
                                                   float* __restrict__ out) {
  const int lane = threadIdx.x & 63;
  const size_t row = (size_t)blockIdx.x * 4 + (threadIdx.x >> 6);
  s16x8 zv = *(const s16x8*)(Z + row * BD + lane * 8);
  float v[8];
#pragma unroll
  for (int j = 0; j < 8; ++j) v[j] = bf2f((u16)zv[j]);
  float s = 0.f, s2 = 0.f;
#pragma unroll
  for (int j = 0; j < 8; ++j) { s += v[j]; s2 += v[j] * v[j]; }
#pragma unroll
  for (int m = 1; m < 64; m <<= 1) { s += __shfl_xor(s, m); s2 += __shfl_xor(s2, m); }
  float mean = s * (1.f / BD);
  float rstd = rsqrtf(s2 * (1.f / BD) - mean * mean + 1e-5f);
  const float* gp = g + lane * 8;
  const float* bp = be + lane * 8;
  f32x4 o0, o1;
#pragma unroll
  for (int j = 0; j < 4; ++j) o0[j] = (v[j] - mean) * rstd * gp[j] + bp[j];
#pragma unroll
  for (int j = 0; j < 4; ++j) o1[j] = (v[4 + j] - mean) * rstd * gp[4 + j] + bp[4 + j];
  float* op = out + row * BD + lane * 8;
  *(f32x4*)op = o0;
  *(f32x4*)(op + 4) = o1;
}

// ---------------- NT GEMM: C[M,*] = A[M,K] @ W[N,K]^T + bias --------------
// TM: 128 or 64. SWZ=1: 1-D grid of 1024, XCD-aware (m,n) remap so the 4
// N-blocks sharing an A-tile run on one XCD (A read ~once from HBM).
// EPI 0: bf16 out; 1: gelu+bf16; 2: +resid bf16; 3: dual K/V out, V transposed
template <int TM, int EPI, int SWZ>
__global__ __launch_bounds__(256, 2) void gemm_nt(const u16* __restrict__ A,
                                                  const u16* __restrict__ W,
                                                  const float* __restrict__ bias,
                                                  u16* __restrict__ C,
                                                  const u16* __restrict__ resid,
                                                  u16* __restrict__ C2,
                                                  const float* __restrict__ bias2,
                                                  int K) {
  constexpr int MT = 4;
  constexpr int NT = (TM == 128) ? 4 : 2;
  __shared__ u16 As[TM * 32];
  __shared__ u16 Bs[128 * 32];
  const int tid = threadIdx.x;
  const int wave = tid >> 6, lane = tid & 63;
  const int wm = (TM == 128) ? (wave & 1) * 64 : 0;
  const int wn = (TM == 128) ? (wave >> 1) * 64 : wave * 32;
  const int quad = lane >> 4, l16 = lane & 15;
  int m_t, n_t;
  if (SWZ) {  // 256 M-tiles x 4 N-tiles; bid&7 = XCD slot
    const int bid = blockIdx.x;
    const int xcd = bid & 7, j = bid >> 3;
    n_t = j & 3;
    m_t = xcd + (j >> 2) * 8;
  } else {
    m_t = blockIdx.x; n_t = blockIdx.y;
  }
  const int m0 = m_t * TM, n0 = n_t * 128;

  f32x4 acc[MT][NT];
#pragma unroll
  for (int i = 0; i < MT; ++i)
#pragma unroll
    for (int j = 0; j < NT; ++j) acc[i][j] = f32x4{0.f, 0.f, 0.f, 0.f};

  const int scol = (lane & 3) * 8;
  const int srowA = (TM == 128) ? wave * 32 + (lane >> 2) : wave * 16 + (lane >> 2);
  const int srowB = wave * 32 + (lane >> 2);
  const u16* gA0 = A + (size_t)(m0 + srowA) * K + scol;
  const u16* gA1 = gA0 + (size_t)16 * K;   // only used when TM==128
  const u16* gW0 = W + (size_t)(n0 + srowB) * K + scol;
  const u16* gW1 = gW0 + (size_t)16 * K;
  u16* lA = As + ((TM == 128) ? wave * 1024 : wave * 512);
  u16* lB = Bs + wave * 1024;

  for (int k0 = 0; k0 < K; k0 += 32) {
    __syncthreads();
    gl_lds16(gA0 + k0, lA);
    if (TM == 128) gl_lds16(gA1 + k0, lA + 512);
    gl_lds16(gW0 + k0, lB);
    gl_lds16(gW1 + k0, lB + 512);
    __syncthreads();
    s16x8 af[MT], bfr[NT];
#pragma unroll
    for (int mt = 0; mt < MT; ++mt)
      af[mt] = *(const s16x8*)&As[(wm + mt * 16 + l16) * 32 + quad * 8];
#pragma unroll
    for (int nt = 0; nt < NT; ++nt)
      bfr[nt] = *(const s16x8*)&Bs[(wn + nt * 16 + l16) * 32 + quad * 8];
#pragma unroll
    for (int mt = 0; mt < MT; ++mt)
#pragma unroll
      for (int nt = 0; nt < NT; ++nt)
        acc[mt][nt] = mfma16(af[mt], bfr[nt], acc[mt][nt]);
  }

#pragma unroll
  for (int nt = 0; nt < NT; ++nt) {
    const int n = n0 + wn + nt * 16 + l16;
    const float bia = (EPI == 3) ? (n < BD ? bias[n] : bias2[n - BD]) : bias[n];
#pragma unroll
    for (int mt = 0; mt < MT; ++mt) {
      const int mb = m0 + wm + mt * 16 + quad * 4;
      if (EPI == 3 && n >= BD) {
        // V out, transposed: VT[b][n-512][k], b = m>>8, k = m&255 (8B store)
        u16x4 pk;
#pragma unroll
        for (int r = 0; r < 4; ++r) pk[r] = f2bf(acc[mt][nt][r] + bia);
        const int b = mb >> 8, k0i = mb & 255;
        *(u16x4*)&C2[((size_t)b * BD + (n - BD)) * LYK + k0i] = pk;
      } else {
#pragma unroll
        for (int r = 0; r < 4; ++r) {
          float v = acc[mt][nt][r] + bia;
          size_t idx = (size_t)(mb + r) * BD + n;
          if (EPI == 1) v = 0.5f * v * (1.f + erff(v * 0.70710678118654752f));
          if (EPI == 2) v += bf2f(resid[idx]);
          C[idx] = f2bf(v);
        }
      }
    }
  }
}

// ---------------- attention: per (qtile64, head, batch) -------------------
// VT staged coalesced into LDS (shared); K B-frags straight from global
// (32KB slice -> L1); P per-wave in LDS (no barrier needed). Exactly one
// __syncthreads, covered by the QK/softmax phase. 66KB LDS -> 2 WG/CU.
__global__ __launch_bounds__(256, 2) void attn_k(const u16* __restrict__ Q,
                                                 const u16* __restrict__ Kg,
                                                 const u16* __restrict__ VT,
                                                 const int* __restrict__ off,
                                                 u16* __restrict__ O) {
  const int t = blockIdx.x, h = blockIdx.y, b = blockIdx.z;
  const int qend = off[b + 1];
  const int qstart = off[b] + t * 64;
  if (qstart >= qend) return;

  __shared__ u16 VTs[64 * 264];       // V^T tile [d=64][key=256], stride 264
  __shared__ u16 Ps[4 * 16 * 264];    // per-wave P [16][256], stride 264

  const int tid = threadIdx.x;
  const int wave = tid >> 6, lane = tid & 63;
  const int quad = lane >> 4, l16 = lane & 15;

  // stage VT slice (rows contiguous in global -> fully coalesced b128)
  const u16* vsrc = VT + ((size_t)b * BD + h * 64) * LYK;
#pragma unroll
  for (int s = 0; s < 8; ++s) {
    int seg = tid + s * 256;            // 2048 chunks of 16B
    int r = seg >> 5, c = (seg & 31) * 8;
    *(s16x8*)&VTs[r * 264 + c] = *(const s16x8*)&vsrc[(size_t)r * LYK + c];
  }

  // Q A-frags from global (m=l16, k=quad*8+j)
  int qrow = qstart + wave * 16 + l16;
  if (qrow > NTOK - 1) qrow = NTOK - 1;
  const u16* qp = Q + (size_t)qrow * BD + h * 64 + quad * 8;
  s16x8 aq0 = *(const s16x8*)qp;
  s16x8 aq1 = *(const s16x8*)(qp + 32);

  // S = Q K^T; K B-frags from global (rows 512B apart, 4 quads/line)
  const u16* kb = Kg + (size_t)b * LYK * BD + h * 64;
  f32x4 sacc[16];
#pragma unroll
  for (int nt = 0; nt < 16; ++nt) sacc[nt] = f32x4{0.f, 0.f, 0.f, 0.f};
#pragma unroll
  for (int nt = 0; nt < 16; ++nt) {
    const u16* kp = kb + (size_t)(nt * 16 + l16) * BD + quad * 8;
    s16x8 b0 = *(const s16x8*)kp;
    s16x8 b1 = *(const s16x8*)(kp + 32);
    sacc[nt] = mfma16(aq0, b0, sacc[nt]);
    sacc[nt] = mfma16(aq1, b1, sacc[nt]);
  }

  // softmax over 256 keys; C-row (quad*4+r) spread over this quad's 16 lanes
  float inv[4];
#pragma unroll
  for (int r = 0; r < 4; ++r) {
    float m = -1e30f;
#pragma unroll
    for (int nt = 0; nt < 16; ++nt) m = fmaxf(m, sacc[nt][r]);
#pragma unroll
    for (int msk = 1; msk < 16; msk <<= 1) m = fmaxf(m, __shfl_xor(m, msk));
    float sum = 0.f;
#pragma unroll
    for (int nt = 0; nt < 16; ++nt) {
      float p = __expf(0.125f * (sacc[nt][r] - m));  // dh^-0.5 = 0.125
      sacc[nt][r] = p;
      sum += p;
    }
#pragma unroll
    for (int msk = 1; msk < 16; msk <<= 1) sum += __shfl_xor(sum, msk);
    inv[r] = 1.f / sum;
  }

  // per-wave P (unnormalized bf16); no cross-wave hazard
  u16* Pw = Ps + wave * (16 * 264);
#pragma unroll
  for (int nt = 0; nt < 16; ++nt)
#pragma unroll
    for (int r = 0; r < 4; ++r)
      Pw[(quad * 4 + r) * 264 + nt * 16 + l16] = f2bf(sacc[nt][r]);

  __syncthreads();  // VTs staged (latency covered by QK + softmax above)

  // O = P V : M=16, N=64, K=256, all from LDS
  f32x4 oacc[4];
#pragma unroll
  for (int n2 = 0; n2 < 4; ++n2) oacc[n2] = f32x4{0.f, 0.f, 0.f, 0.f};
#pragma unroll
  for (int kc = 0; kc < 8; ++kc) {
    s16x8 ap = *(const s16x8*)&Pw[l16 * 264 + kc * 32 + quad * 8];
#pragma unroll
    for (int n2 = 0; n2 < 4; ++n2) {
      s16x8 bv = *(const s16x8*)&VTs[(n2 * 16 + l16) * 264 + kc * 32 + quad * 8];
      oacc[n2] = mfma16(ap, bv, oacc[n2]);
    }
  }

#pragma unroll
  for (int n2 = 0; n2 < 4; ++n2)
#pragma unroll
    for (int r = 0; r < 4; ++r) {
      int q = qstart + wave * 16 + quad * 4 + r;
      if (q < qend)
        O[(size_t)q * BD + h * 64 + n2 * 16 + l16] = f2bf(oacc[n2][r] * inv[r]);
    }
}

extern "C" void kernel_launch(void* const* d_in, const int* in_sizes, int n_in,
                              void* d_out, int out_size, void* d_ws, size_t ws_size,
                              hipStream_t stream) {
  const float* F    = (const float*)d_in[0];
  const float* yIn  = (const float*)d_in[1];
  const float* ln_g = (const float*)d_in[2];
  const float* ln_b = (const float*)d_in[3];
  const float* Wq   = (const float*)d_in[4];
  const float* Wk   = (const float*)d_in[5];
  const float* Wv   = (const float*)d_in[6];
  const float* bq   = (const float*)d_in[7];
  const float* bk   = (const float*)d_in[8];
  const float* bv   = (const float*)d_in[9];
  const float* Wo   = (const float*)d_in[10];
  const float* bo   = (const float*)d_in[11];
  const float* W1   = (const float*)d_in[12];
  const float* b1   = (const float*)d_in[13];
  const float* W2   = (const float*)d_in[14];
  const float* b2   = (const float*)d_in[15];
  const int* bids   = (const int*)d_in[16];

  char* ws = (char*)d_ws;
  size_t cur = 0;
  auto alloc = [&](size_t bytes) {
    void* p = ws + cur;
    cur += (bytes + 255) & ~(size_t)255;
    return p;
  };

  int* off   = (int*)alloc(68);
  u16* wq_b  = (u16*)alloc((size_t)262144 * 2);
  u16* wkv_b = (u16*)alloc((size_t)524288 * 2);   // [Wk; Wv] stacked, 1024x512
  u16* wo_b  = (u16*)alloc((size_t)262144 * 2);
  u16* w2_b  = (u16*)alloc((size_t)262144 * 2);
  u16* w1_b  = (u16*)alloc((size_t)393216 * 2);
  u16* y_b   = (u16*)alloc((size_t)3145728 * 2);
  u16* U     = (u16*)alloc((size_t)4096 * BD * 2);
  u16* ym    = (u16*)alloc((size_t)4096 * BD * 2);
  u16* Kb    = (u16*)alloc((size_t)4096 * BD * 2);
  u16* VT    = (u16*)alloc((size_t)NB * BD * LYK * 2);  // [b][dh_full][key]
  u16* xn    = (u16*)alloc((size_t)NTOK * BD * 2);
  u16* Qb    = (u16*)alloc((size_t)NTOK * BD * 2);
  u16* Ob    = (u16*)alloc((size_t)NTOK * BD * 2);
  u16* Zb    = (u16*)alloc((size_t)NTOK * BD * 2);

  prep<<<10561, 256, 0, stream>>>(Wq, Wk, Wv, Wo, W2, W1, yIn, F, ln_g, ln_b, bids,
                                  wq_b, wkv_b, wo_b, w2_b, w1_b, y_b, xn, off);

  // image-feature MLP (M = 4096)
  gemm_nt<64, 1, 0><<<dim3(64, 4), 256, 0, stream>>>(y_b, w1_b, b1, U, nullptr, nullptr, nullptr, IMGD);
  gemm_nt<64, 0, 0><<<dim3(64, 4), 256, 0, stream>>>(U, w2_b, b2, ym, nullptr, nullptr, nullptr, BD);
  // fused K/V projection, N=1024; V written transposed into VT
  gemm_nt<128, 3, 0><<<dim3(32, 8), 256, 0, stream>>>(ym, wkv_b, bk, Kb, nullptr, VT, bv, BD);
  // Q projection (M = 32768), XCD-swizzled 1-D grid
  gemm_nt<128, 0, 1><<<1024, 256, 0, stream>>>(xn, wq_b, bq, Qb, nullptr, nullptr, nullptr, BD);
  // cross-attention on real tokens only
  attn_k<<<dim3(36, 8, NB), 256, 0, stream>>>(Qb, Kb, VT, off, Ob);
  // output projection + residual, XCD-swizzled
  gemm_nt<128, 2, 1><<<1024, 256, 0, stream>>>(Ob, wo_b, bo, Zb, xn, nullptr, nullptr, BD);
  ln_bf16_f32<<<NTOK / 4, 256, 0, stream>>>(Zb, ln_g, ln_b, (float*)d_out);
}

// Round 4
// 365.985 us; speedup vs baseline: 1.0959x; 1.0803x over previous
//
#include <hip/hip_runtime.h>
#include <stdint.h>

#define NTOK 32768
#define BD   512
#define NB   16
#define LYK  256
#define IMGD 768

typedef __attribute__((ext_vector_type(4))) float f32x4;
typedef __attribute__((ext_vector_type(8))) short s16x8;
typedef __attribute__((ext_vector_type(4))) unsigned short u16x4;
typedef unsigned short u16;

__device__ __forceinline__ float bf2f(u16 u) {
  union { uint32_t i; float f; } v; v.i = ((uint32_t)u) << 16; return v.f;
}
__device__ __forceinline__ u16 f2bf(float f) {
  union { float f; uint32_t i; } v; v.f = f;
  uint32_t r = v.i + 0x7fffu + ((v.i >> 16) & 1u);
  return (u16)(r >> 16);
}
__device__ __forceinline__ u16 f2bf_fast(float f) {  // round-half-up, pos inputs
  union { float f; uint32_t i; } v; v.f = f;
  return (u16)((v.i + 0x8000u) >> 16);
}
__device__ __forceinline__ void gl_lds16(const u16* g, u16* l) {
  __builtin_amdgcn_global_load_lds(
      (const __attribute__((address_space(1))) uint32_t*)g,
      (__attribute__((address_space(3))) uint32_t*)l, 16, 0, 0);
}
__device__ __forceinline__ f32x4 mfma16(s16x8 a, s16x8 b, f32x4 c) {
  return __builtin_amdgcn_mfma_f32_16x16x32_bf16(a, b, c, 0, 0, 0);
}

// ---- prep: fused fp32->bf16 converts + LayerNorm(F) + batch offsets ------
__global__ __launch_bounds__(256) void prep(
    const float* __restrict__ wq, const float* __restrict__ wk,
    const float* __restrict__ wv, const float* __restrict__ wo,
    const float* __restrict__ w2, const float* __restrict__ w1,
    const float* __restrict__ y,  const float* __restrict__ F,
    const float* __restrict__ g,  const float* __restrict__ be,
    const int* __restrict__ bids,
    u16* __restrict__ dq, u16* __restrict__ dkv, u16* __restrict__ dwo,
    u16* __restrict__ dw2, u16* __restrict__ dw1, u16* __restrict__ dy,
    u16* __restrict__ xn, int* __restrict__ off) {
  const int bid = blockIdx.x;
  if (bid < 2368) {
    const float* s; u16* d; int base;
    if      (bid < 128)  { s = wq; d = dq;            base = 0;   }
    else if (bid < 256)  { s = wk; d = dkv;           base = 128; }
    else if (bid < 384)  { s = wv; d = dkv + 262144;  base = 256; }
    else if (bid < 512)  { s = wo; d = dwo;           base = 384; }
    else if (bid < 640)  { s = w2; d = dw2;           base = 512; }
    else if (bid < 832)  { s = w1; d = dw1;           base = 640; }
    else                 { s = y;  d = dy;            base = 832; }
    int i = ((bid - base) * 256 + threadIdx.x) * 8;
    f32x4 a = *(const f32x4*)(s + i);
    f32x4 b = *(const f32x4*)(s + i + 4);
    s16x8 o;
#pragma unroll
    for (int j = 0; j < 4; ++j) { o[j] = (short)f2bf(a[j]); o[4 + j] = (short)f2bf(b[j]); }
    *(s16x8*)(d + i) = o;
  } else if (bid < 10560) {
    const int lane = threadIdx.x & 63;
    const size_t row = (size_t)(bid - 2368) * 4 + (threadIdx.x >> 6);
    const float* x = F + row * BD + lane * 8;
    f32x4 a = *(const f32x4*)x;
    f32x4 b = *(const f32x4*)(x + 4);
    float v[8] = {a[0], a[1], a[2], a[3], b[0], b[1], b[2], b[3]};
    float s = 0.f, s2 = 0.f;
#pragma unroll
    for (int j = 0; j < 8; ++j) { s += v[j]; s2 += v[j] * v[j]; }
#pragma unroll
    for (int m = 1; m < 64; m <<= 1) { s += __shfl_xor(s, m); s2 += __shfl_xor(s2, m); }
    float mean = s * (1.f / BD);
    float rstd = rsqrtf(s2 * (1.f / BD) - mean * mean + 1e-5f);
    const float* gp = g + lane * 8;
    const float* bp = be + lane * 8;
    s16x8 o;
#pragma unroll
    for (int j = 0; j < 8; ++j) o[j] = (short)f2bf((v[j] - mean) * rstd * gp[j] + bp[j]);
    *(s16x8*)(xn + row * BD + lane * 8) = o;
  } else {
    int b = threadIdx.x;
    if (b > NB) return;
    int lo = 0, hi = NTOK;
    while (lo < hi) { int mid = (lo + hi) >> 1; if (bids[mid] < b) lo = mid + 1; else hi = mid; }
    off[b] = lo;
  }
}

// ---------------- LayerNorm: bf16 in -> fp32 out ----------------
__global__ __launch_bounds__(256) void ln_bf16_f32(const u16* __restrict__ Z,
                                                   const float* __restrict__ g,
                                                   const float* __restrict__ be,
                                                   float* __restrict__ out) {
  const int lane = threadIdx.x & 63;
  const size_t row = (size_t)blockIdx.x * 4 + (threadIdx.x >> 6);
  s16x8 zv = *(const s16x8*)(Z + row * BD + lane * 8);
  float v[8];
#pragma unroll
  for (int j = 0; j < 8; ++j) v[j] = bf2f((u16)zv[j]);
  float s = 0.f, s2 = 0.f;
#pragma unroll
  for (int j = 0; j < 8; ++j) { s += v[j]; s2 += v[j] * v[j]; }
#pragma unroll
  for (int m = 1; m < 64; m <<= 1) { s += __shfl_xor(s, m); s2 += __shfl_xor(s2, m); }
  float mean = s * (1.f / BD);
  float rstd = rsqrtf(s2 * (1.f / BD) - mean * mean + 1e-5f);
  const float* gp = g + lane * 8;
  const float* bp = be + lane * 8;
  f32x4 o0, o1;
#pragma unroll
  for (int j = 0; j < 4; ++j) o0[j] = (v[j] - mean) * rstd * gp[j] + bp[j];
#pragma unroll
  for (int j = 0; j < 4; ++j) o1[j] = (v[4 + j] - mean) * rstd * gp[4 + j] + bp[4 + j];
  float* op = out + row * BD + lane * 8;
  *(f32x4*)op = o0;
  *(f32x4*)(op + 4) = o1;
}

// ---------------- TM=64 NT GEMM (small M), BK=32 --------------------------
template <int EPI>
__global__ __launch_bounds__(256, 2) void gemm64(const u16* __restrict__ A,
                                                 const u16* __restrict__ W,
                                                 const float* __restrict__ bias,
                                                 u16* __restrict__ C, int K) {
  __shared__ u16 As[64 * 32];
  __shared__ u16 Bs[128 * 32];
  const int tid = threadIdx.x;
  const int wave = tid >> 6, lane = tid & 63;
  const int wn = wave * 32;
  const int quad = lane >> 4, l16 = lane & 15;
  const int m0 = blockIdx.x * 64, n0 = blockIdx.y * 128;

  f32x4 acc[4][2];
#pragma unroll
  for (int i = 0; i < 4; ++i)
#pragma unroll
    for (int j = 0; j < 2; ++j) acc[i][j] = f32x4{0.f, 0.f, 0.f, 0.f};

  const int scol = (lane & 3) * 8;
  const u16* gA0 = A + (size_t)(m0 + wave * 16 + (lane >> 2)) * K + scol;
  const u16* gW0 = W + (size_t)(n0 + wave * 32 + (lane >> 2)) * K + scol;
  const u16* gW1 = gW0 + (size_t)16 * K;
  u16* lA = As + wave * 512;
  u16* lB = Bs + wave * 1024;

  for (int k0 = 0; k0 < K; k0 += 32) {
    __syncthreads();
    gl_lds16(gA0 + k0, lA);
    gl_lds16(gW0 + k0, lB);
    gl_lds16(gW1 + k0, lB + 512);
    __syncthreads();
    s16x8 af[4], bfr[2];
#pragma unroll
    for (int mt = 0; mt < 4; ++mt)
      af[mt] = *(const s16x8*)&As[(mt * 16 + l16) * 32 + quad * 8];
#pragma unroll
    for (int nt = 0; nt < 2; ++nt)
      bfr[nt] = *(const s16x8*)&Bs[(wn + nt * 16 + l16) * 32 + quad * 8];
#pragma unroll
    for (int mt = 0; mt < 4; ++mt)
#pragma unroll
      for (int nt = 0; nt < 2; ++nt)
        acc[mt][nt] = mfma16(af[mt], bfr[nt], acc[mt][nt]);
  }

#pragma unroll
  for (int nt = 0; nt < 2; ++nt) {
    const int n = n0 + wn + nt * 16 + l16;
    const float bia = bias[n];
#pragma unroll
    for (int mt = 0; mt < 4; ++mt) {
      const int mb = m0 + mt * 16 + quad * 4;
#pragma unroll
      for (int r = 0; r < 4; ++r) {
        float v = acc[mt][nt][r] + bia;
        if (EPI == 1) v = 0.5f * v * (1.f + erff(v * 0.70710678118654752f));
        C[(size_t)(mb + r) * BD + n] = f2bf(v);
      }
    }
  }
}

// ---------------- TM=128 NT GEMM, BK=64 -----------------------------------
// EPI 0: bf16 out; 2: +resid bf16; 3: dual K/V out, V transposed into C2
template <int EPI, int SWZ>
__global__ __launch_bounds__(256, 2) void gemm128(const u16* __restrict__ A,
                                                  const u16* __restrict__ W,
                                                  const float* __restrict__ bias,
                                                  u16* __restrict__ C,
                                                  const u16* __restrict__ resid,
                                                  u16* __restrict__ C2,
                                                  const float* __restrict__ bias2,
                                                  int K) {
  __shared__ u16 As[128 * 64];
  __shared__ u16 Bs[128 * 64];
  const int tid = threadIdx.x;
  const int wave = tid >> 6, lane = tid & 63;
  const int wm = (wave & 1) * 64, wn = (wave >> 1) * 64;
  const int quad = lane >> 4, l16 = lane & 15;
  int m_t, n_t;
  if (SWZ) {  // bid&7 = XCD slot; N-blocks sharing an A-tile on one XCD
    const int bid = blockIdx.x;
    const int xcd = bid & 7, j = bid >> 3;
    n_t = j & 3;
    m_t = xcd + (j >> 2) * 8;
  } else {
    m_t = blockIdx.x; n_t = blockIdx.y;
  }
  const int m0 = m_t * 128, n0 = n_t * 128;

  f32x4 acc[4][4];
#pragma unroll
  for (int i = 0; i < 4; ++i)
#pragma unroll
    for (int j = 0; j < 4; ++j) acc[i][j] = f32x4{0.f, 0.f, 0.f, 0.f};

  // staging: chunk c = wave*256 + s*64 + lane; row=c>>3, col=(c&7)*8
  const int srow = wave * 32 + (lane >> 3);
  const int scol = (lane & 7) * 8;
  const u16* gA = A + (size_t)(m0 + srow) * K + scol;
  const u16* gW = W + (size_t)(n0 + srow) * K + scol;
  u16* lA = As + wave * 2048;
  u16* lB = Bs + wave * 2048;

  for (int k0 = 0; k0 < K; k0 += 64) {
    __syncthreads();
#pragma unroll
    for (int s = 0; s < 4; ++s) gl_lds16(gA + (size_t)s * 8 * K + k0, lA + s * 512);
#pragma unroll
    for (int s = 0; s < 4; ++s) gl_lds16(gW + (size_t)s * 8 * K + k0, lB + s * 512);
    __syncthreads();
    s16x8 af[4][2], bfr[4][2];
#pragma unroll
    for (int mt = 0; mt < 4; ++mt)
#pragma unroll
      for (int ks = 0; ks < 2; ++ks)
        af[mt][ks] = *(const s16x8*)&As[(wm + mt * 16 + l16) * 64 + ks * 32 + quad * 8];
#pragma unroll
    for (int nt = 0; nt < 4; ++nt)
#pragma unroll
      for (int ks = 0; ks < 2; ++ks)
        bfr[nt][ks] = *(const s16x8*)&Bs[(wn + nt * 16 + l16) * 64 + ks * 32 + quad * 8];
#pragma unroll
    for (int ks = 0; ks < 2; ++ks)
#pragma unroll
      for (int mt = 0; mt < 4; ++mt)
#pragma unroll
        for (int nt = 0; nt < 4; ++nt)
          acc[mt][nt] = mfma16(af[mt][ks], bfr[nt][ks], acc[mt][nt]);
  }

#pragma unroll
  for (int nt = 0; nt < 4; ++nt) {
    const int n = n0 + wn + nt * 16 + l16;
    const float bia = (EPI == 3) ? (n < BD ? bias[n] : bias2[n - BD]) : bias[n];
#pragma unroll
    for (int mt = 0; mt < 4; ++mt) {
      const int mb = m0 + wm + mt * 16 + quad * 4;
      if (EPI == 3 && n >= BD) {
        u16x4 pk;  // V out transposed: VT[b][n-512][k], b=m>>8, k=m&255
#pragma unroll
        for (int r = 0; r < 4; ++r) pk[r] = f2bf(acc[mt][nt][r] + bia);
        const int b = mb >> 8, k0i = mb & 255;
        *(u16x4*)&C2[((size_t)b * BD + (n - BD)) * LYK + k0i] = pk;
      } else {
#pragma unroll
        for (int r = 0; r < 4; ++r) {
          float v = acc[mt][nt][r] + bia;
          size_t idx = (size_t)(mb + r) * BD + n;
          if (EPI == 2) v += bf2f(resid[idx]);
          C[idx] = f2bf(v);
        }
      }
    }
  }
}

// ---------------- attention: per (qtile64, head, batch) -------------------
// S^T = K*Q^T trick: each lane's scores all belong to query l16 -> softmax
// is in-lane + 2 shuffles, P write-back is b64-vectorized. Both K and VT
// staged in LDS (coalesced b128); P overlays the K region after one barrier.
__global__ __launch_bounds__(256, 2) void attn_k(const u16* __restrict__ Q,
                                                 const u16* __restrict__ Kg,
                                                 const u16* __restrict__ VT,
                                                 const int* __restrict__ off,
                                                 u16* __restrict__ O) {
  const int t = blockIdx.x, h = blockIdx.y, b = blockIdx.z;
  const int qend = off[b + 1];
  const int qstart = off[b] + t * 64;
  if (qstart >= qend) return;

  __shared__ u16 KT[256 * 72];   // K [key][d], stride 72; later P[64][264]
  __shared__ u16 VTs[64 * 264];  // V^T [d][key], stride 264

  const int tid = threadIdx.x;
  const int wave = tid >> 6, lane = tid & 63;
  const int quad = lane >> 4, l16 = lane & 15;

  {  // stage K_h [256][64] (coalesced 16B chunks)
    const u16* src = Kg + (size_t)b * LYK * BD + h * 64;
#pragma unroll
    for (int s = 0; s < 8; ++s) {
      int c = tid + s * 256;
      int r = c >> 3, col = (c & 7) * 8;
      *(s16x8*)&KT[r * 72 + col] = *(const s16x8*)&src[(size_t)r * BD + col];
    }
  }
  {  // stage V^T slice [64][256] (rows contiguous in global)
    const u16* src = VT + ((size_t)b * BD + h * 64) * LYK;
#pragma unroll
    for (int s = 0; s < 8; ++s) {
      int c = tid + s * 256;
      int r = c >> 5, col = (c & 31) * 8;
      *(s16x8*)&VTs[r * 264 + col] = *(const s16x8*)&src[(size_t)r * LYK + col];
    }
  }
  // Q fragments (B-operand; n=l16 -> query)
  int qrow = qstart + wave * 16 + l16;
  if (qrow > NTOK - 1) qrow = NTOK - 1;
  const u16* qp = Q + (size_t)qrow * BD + h * 64 + quad * 8;
  s16x8 aq0 = *(const s16x8*)qp;
  s16x8 aq1 = *(const s16x8*)(qp + 32);

  __syncthreads();

  // S^T = K Q^T : D[m=key][n=query]; lane holds keys nt*16+quad*4+r, query l16
  f32x4 sacc[16];
#pragma unroll
  for (int nt = 0; nt < 16; ++nt) sacc[nt] = f32x4{0.f, 0.f, 0.f, 0.f};
#pragma unroll
  for (int nt = 0; nt < 16; ++nt) {
    const u16* kp = &KT[(nt * 16 + l16) * 72 + quad * 8];
    s16x8 k0 = *(const s16x8*)kp;
    s16x8 k1 = *(const s16x8*)(kp + 32);
    sacc[nt] = mfma16(k0, aq0, sacc[nt]);
    sacc[nt] = mfma16(k1, aq1, sacc[nt]);
  }

  // softmax for query l16: in-lane reduce over 64 vals + 2 quad-shuffles
  float mx = -1e30f;
#pragma unroll
  for (int nt = 0; nt < 16; ++nt)
#pragma unroll
    for (int r = 0; r < 4; ++r) mx = fmaxf(mx, sacc[nt][r]);
  mx = fmaxf(mx, __shfl_xor(mx, 16));
  mx = fmaxf(mx, __shfl_xor(mx, 32));
  float sum = 0.f;
#pragma unroll
  for (int nt = 0; nt < 16; ++nt)
#pragma unroll
    for (int r = 0; r < 4; ++r) {
      float p = __expf(0.125f * (sacc[nt][r] - mx));
      sacc[nt][r] = p;
      sum += p;
    }
  sum += __shfl_xor(sum, 16);
  sum += __shfl_xor(sum, 32);
  const float inv = 1.f / sum;

  __syncthreads();  // all waves done reading KT before P overlays it

  // P[query][key], stride 264, normalized bf16; b64 writes (4 keys/lane)
  u16* P = KT;
  const int prow = (wave * 16 + l16) * 264;
#pragma unroll
  for (int nt = 0; nt < 16; ++nt) {
    u16x4 pk;
#pragma unroll
    for (int r = 0; r < 4; ++r) pk[r] = f2bf_fast(sacc[nt][r] * inv);
    *(u16x4*)&P[prow + nt * 16 + quad * 4] = pk;
  }

  // O = P V : A-frags from own wave's P rows (no barrier needed), B from VTs
  f32x4 oacc[4];
#pragma unroll
  for (int n2 = 0; n2 < 4; ++n2) oacc[n2] = f32x4{0.f, 0.f, 0.f, 0.f};
#pragma unroll
  for (int kc = 0; kc < 8; ++kc) {
    s16x8 ap = *(const s16x8*)&P[prow + kc * 32 + quad * 8];
#pragma unroll
    for (int n2 = 0; n2 < 4; ++n2) {
      s16x8 bv = *(const s16x8*)&VTs[(n2 * 16 + l16) * 264 + kc * 32 + quad * 8];
      oacc[n2] = mfma16(ap, bv, oacc[n2]);
    }
  }

#pragma unroll
  for (int n2 = 0; n2 < 4; ++n2)
#pragma unroll
    for (int r = 0; r < 4; ++r) {
      int q = qstart + wave * 16 + quad * 4 + r;
      if (q < qend)
        O[(size_t)q * BD + h * 64 + n2 * 16 + l16] = f2bf(oacc[n2][r]);
    }
}

extern "C" void kernel_launch(void* const* d_in, const int* in_sizes, int n_in,
                              void* d_out, int out_size, void* d_ws, size_t ws_size,
                              hipStream_t stream) {
  const float* F    = (const float*)d_in[0];
  const float* yIn  = (const float*)d_in[1];
  const float* ln_g = (const float*)d_in[2];
  const float* ln_b = (const float*)d_in[3];
  const float* Wq   = (const float*)d_in[4];
  const float* Wk   = (const float*)d_in[5];
  const float* Wv   = (const float*)d_in[6];
  const float* bq   = (const float*)d_in[7];
  const float* bk   = (const float*)d_in[8];
  const float* bv   = (const float*)d_in[9];
  const float* Wo   = (const float*)d_in[10];
  const float* bo   = (const float*)d_in[11];
  const float* W1   = (const float*)d_in[12];
  const float* b1   = (const float*)d_in[13];
  const float* W2   = (const float*)d_in[14];
  const float* b2   = (const float*)d_in[15];
  const int* bids   = (const int*)d_in[16];

  char* ws = (char*)d_ws;
  size_t cur = 0;
  auto alloc = [&](size_t bytes) {
    void* p = ws + cur;
    cur += (bytes + 255) & ~(size_t)255;
    return p;
  };

  int* off   = (int*)alloc(68);
  u16* wq_b  = (u16*)alloc((size_t)262144 * 2);
  u16* wkv_b = (u16*)alloc((size_t)524288 * 2);   // [Wk; Wv] stacked, 1024x512
  u16* wo_b  = (u16*)alloc((size_t)262144 * 2);
  u16* w2_b  = (u16*)alloc((size_t)262144 * 2);
  u16* w1_b  = (u16*)alloc((size_t)393216 * 2);
  u16* y_b   = (u16*)alloc((size_t)3145728 * 2);
  u16* U     = (u16*)alloc((size_t)4096 * BD * 2);
  u16* ym    = (u16*)alloc((size_t)4096 * BD * 2);
  u16* Kb    = (u16*)alloc((size_t)4096 * BD * 2);
  u16* VT    = (u16*)alloc((size_t)NB * BD * LYK * 2);  // [b][dh_full][key]
  u16* xn    = (u16*)alloc((size_t)NTOK * BD * 2);
  u16* Qb    = (u16*)alloc((size_t)NTOK * BD * 2);
  u16* Ob    = (u16*)alloc((size_t)NTOK * BD * 2);
  u16* Zb    = (u16*)alloc((size_t)NTOK * BD * 2);

  prep<<<10561, 256, 0, stream>>>(Wq, Wk, Wv, Wo, W2, W1, yIn, F, ln_g, ln_b, bids,
                                  wq_b, wkv_b, wo_b, w2_b, w1_b, y_b, xn, off);

  // image-feature MLP (M = 4096)
  gemm64<1><<<dim3(64, 4), 256, 0, stream>>>(y_b, w1_b, b1, U, IMGD);
  gemm64<0><<<dim3(64, 4), 256, 0, stream>>>(U, w2_b, b2, ym, BD);
  // fused K/V projection, N=1024; V written transposed into VT
  gemm128<3, 0><<<dim3(32, 8), 256, 0, stream>>>(ym, wkv_b, bk, Kb, nullptr, VT, bv, BD);
  // Q projection (M = 32768), XCD-swizzled 1-D grid
  gemm128<0, 1><<<1024, 256, 0, stream>>>(xn, wq_b, bq, Qb, nullptr, nullptr, nullptr, BD);
  // cross-attention on real tokens only
  attn_k<<<dim3(36, 8, NB), 256, 0, stream>>>(Qb, Kb, VT, off, Ob);
  // output projection + residual, XCD-swizzled
  gemm128<2, 1><<<1024, 256, 0, stream>>>(Ob, wo_b, bo, Zb, xn, nullptr, nullptr, BD);
  ln_bf16_f32<<<NTOK / 4, 256, 0, stream>>>(Zb, ln_g, ln_b, (float*)d_out);
}

// Round 5
// 334.972 us; speedup vs baseline: 1.1973x; 1.0926x over previous
//
#include <hip/hip_runtime.h>
#include <stdint.h>

#define NTOK 32768
#define BD   512
#define NB   16
#define LYK  256
#define IMGD 768

typedef __attribute__((ext_vector_type(4))) float f32x4;
typedef __attribute__((ext_vector_type(8))) short s16x8;
typedef __attribute__((ext_vector_type(4))) unsigned short u16x4;
typedef unsigned short u16;

__device__ __forceinline__ float bf2f(u16 u) {
  union { uint32_t i; float f; } v; v.i = ((uint32_t)u) << 16; return v.f;
}
__device__ __forceinline__ u16 f2bf(float f) {
  union { float f; uint32_t i; } v; v.f = f;
  uint32_t r = v.i + 0x7fffu + ((v.i >> 16) & 1u);
  return (u16)(r >> 16);
}
__device__ __forceinline__ u16 f2bf_fast(float f) {  // round-half-up, pos inputs
  union { float f; uint32_t i; } v; v.f = f;
  return (u16)((v.i + 0x8000u) >> 16);
}
__device__ __forceinline__ void gl_lds16(const u16* g, u16* l) {
  __builtin_amdgcn_global_load_lds(
      (const __attribute__((address_space(1))) uint32_t*)g,
      (__attribute__((address_space(3))) uint32_t*)l, 16, 0, 0);
}
__device__ __forceinline__ f32x4 mfma16(s16x8 a, s16x8 b, f32x4 c) {
  return __builtin_amdgcn_mfma_f32_16x16x32_bf16(a, b, c, 0, 0, 0);
}

// ---- prep: fused fp32->bf16 converts + LayerNorm(F) + batch offsets ------
__global__ __launch_bounds__(256) void prep(
    const float* __restrict__ wq, const float* __restrict__ wk,
    const float* __restrict__ wv, const float* __restrict__ wo,
    const float* __restrict__ w2, const float* __restrict__ w1,
    const float* __restrict__ y,  const float* __restrict__ F,
    const float* __restrict__ g,  const float* __restrict__ be,
    const int* __restrict__ bids,
    u16* __restrict__ dq, u16* __restrict__ dkv, u16* __restrict__ dwo,
    u16* __restrict__ dw2, u16* __restrict__ dw1, u16* __restrict__ dy,
    u16* __restrict__ xn, int* __restrict__ off) {
  const int bid = blockIdx.x;
  if (bid < 2368) {
    const float* s; u16* d; int base;
    if      (bid < 128)  { s = wq; d = dq;            base = 0;   }
    else if (bid < 256)  { s = wk; d = dkv;           base = 128; }
    else if (bid < 384)  { s = wv; d = dkv + 262144;  base = 256; }
    else if (bid < 512)  { s = wo; d = dwo;           base = 384; }
    else if (bid < 640)  { s = w2; d = dw2;           base = 512; }
    else if (bid < 832)  { s = w1; d = dw1;           base = 640; }
    else                 { s = y;  d = dy;            base = 832; }
    int i = ((bid - base) * 256 + threadIdx.x) * 8;
    f32x4 a = *(const f32x4*)(s + i);
    f32x4 b = *(const f32x4*)(s + i + 4);
    s16x8 o;
#pragma unroll
    for (int j = 0; j < 4; ++j) { o[j] = (short)f2bf(a[j]); o[4 + j] = (short)f2bf(b[j]); }
    *(s16x8*)(d + i) = o;
  } else if (bid < 10560) {
    const int lane = threadIdx.x & 63;
    const size_t row = (size_t)(bid - 2368) * 4 + (threadIdx.x >> 6);
    const float* x = F + row * BD + lane * 8;
    f32x4 a = *(const f32x4*)x;
    f32x4 b = *(const f32x4*)(x + 4);
    float v[8] = {a[0], a[1], a[2], a[3], b[0], b[1], b[2], b[3]};
    float s = 0.f, s2 = 0.f;
#pragma unroll
    for (int j = 0; j < 8; ++j) { s += v[j]; s2 += v[j] * v[j]; }
#pragma unroll
    for (int m = 1; m < 64; m <<= 1) { s += __shfl_xor(s, m); s2 += __shfl_xor(s2, m); }
    float mean = s * (1.f / BD);
    float rstd = rsqrtf(s2 * (1.f / BD) - mean * mean + 1e-5f);
    const float* gp = g + lane * 8;
    const float* bp = be + lane * 8;
    s16x8 o;
#pragma unroll
    for (int j = 0; j < 8; ++j) o[j] = (short)f2bf((v[j] - mean) * rstd * gp[j] + bp[j]);
    *(s16x8*)(xn + row * BD + lane * 8) = o;
  } else {
    int b = threadIdx.x;
    if (b > NB) return;
    int lo = 0, hi = NTOK;
    while (lo < hi) { int mid = (lo + hi) >> 1; if (bids[mid] < b) lo = mid + 1; else hi = mid; }
    off[b] = lo;
  }
}

// ---------------- LayerNorm: bf16 in -> fp32 out ----------------
__global__ __launch_bounds__(256) void ln_bf16_f32(const u16* __restrict__ Z,
                                                   const float* __restrict__ g,
                                                   const float* __restrict__ be,
                                                   float* __restrict__ out) {
  const int lane = threadIdx.x & 63;
  const size_t row = (size_t)blockIdx.x * 4 + (threadIdx.x >> 6);
  s16x8 zv = *(const s16x8*)(Z + row * BD + lane * 8);
  float v[8];
#pragma unroll
  for (int j = 0; j < 8; ++j) v[j] = bf2f((u16)zv[j]);
  float s = 0.f, s2 = 0.f;
#pragma unroll
  for (int j = 0; j < 8; ++j) { s += v[j]; s2 += v[j] * v[j]; }
#pragma unroll
  for (int m = 1; m < 64; m <<= 1) { s += __shfl_xor(s, m); s2 += __shfl_xor(s2, m); }
  float mean = s * (1.f / BD);
  float rstd = rsqrtf(s2 * (1.f / BD) - mean * mean + 1e-5f);
  const float* gp = g + lane * 8;
  const float* bp = be + lane * 8;
  f32x4 o0, o1;
#pragma unroll
  for (int j = 0; j < 4; ++j) o0[j] = (v[j] - mean) * rstd * gp[j] + bp[j];
#pragma unroll
  for (int j = 0; j < 4; ++j) o1[j] = (v[4 + j] - mean) * rstd * gp[4 + j] + bp[4 + j];
  float* op = out + row * BD + lane * 8;
  *(f32x4*)op = o0;
  *(f32x4*)(op + 4) = o1;
}

// ---------------- TM=64 NT GEMM (small M), BK=32 --------------------------
template <int EPI>
__global__ __launch_bounds__(256, 2) void gemm64(const u16* __restrict__ A,
                                                 const u16* __restrict__ W,
                                                 const float* __restrict__ bias,
                                                 u16* __restrict__ C, int K) {
  __shared__ u16 As[64 * 32];
  __shared__ u16 Bs[128 * 32];
  const int tid = threadIdx.x;
  const int wave = tid >> 6, lane = tid & 63;
  const int wn = wave * 32;
  const int quad = lane >> 4, l16 = lane & 15;
  const int m0 = blockIdx.x * 64, n0 = blockIdx.y * 128;

  f32x4 acc[4][2];
#pragma unroll
  for (int i = 0; i < 4; ++i)
#pragma unroll
    for (int j = 0; j < 2; ++j) acc[i][j] = f32x4{0.f, 0.f, 0.f, 0.f};

  const int scol = (lane & 3) * 8;
  const u16* gA0 = A + (size_t)(m0 + wave * 16 + (lane >> 2)) * K + scol;
  const u16* gW0 = W + (size_t)(n0 + wave * 32 + (lane >> 2)) * K + scol;
  const u16* gW1 = gW0 + (size_t)16 * K;
  u16* lA = As + wave * 512;
  u16* lB = Bs + wave * 1024;

  for (int k0 = 0; k0 < K; k0 += 32) {
    __syncthreads();
    gl_lds16(gA0 + k0, lA);
    gl_lds16(gW0 + k0, lB);
    gl_lds16(gW1 + k0, lB + 512);
    __syncthreads();
    s16x8 af[4], bfr[2];
#pragma unroll
    for (int mt = 0; mt < 4; ++mt)
      af[mt] = *(const s16x8*)&As[(mt * 16 + l16) * 32 + quad * 8];
#pragma unroll
    for (int nt = 0; nt < 2; ++nt)
      bfr[nt] = *(const s16x8*)&Bs[(wn + nt * 16 + l16) * 32 + quad * 8];
#pragma unroll
    for (int mt = 0; mt < 4; ++mt)
#pragma unroll
      for (int nt = 0; nt < 2; ++nt)
        acc[mt][nt] = mfma16(af[mt], bfr[nt], acc[mt][nt]);
  }

#pragma unroll
  for (int nt = 0; nt < 2; ++nt) {
    const int n = n0 + wn + nt * 16 + l16;
    const float bia = bias[n];
#pragma unroll
    for (int mt = 0; mt < 4; ++mt) {
      const int mb = m0 + mt * 16 + quad * 4;
#pragma unroll
      for (int r = 0; r < 4; ++r) {
        float v = acc[mt][nt][r] + bia;
        if (EPI == 1) v = 0.5f * v * (1.f + erff(v * 0.70710678118654752f));
        C[(size_t)(mb + r) * BD + n] = f2bf(v);
      }
    }
  }
}

// ---------------- TM=128 NT GEMM, BK=32, double-buffered ------------------
// One barrier per K-iter: loads for iter k+1 issue after the barrier and
// their vmcnt-drain lands at the NEXT barrier (one MFMA phase of overlap).
// Bank-clean [128][32] layout (row stride 64B -> full-wave conflict-free).
// EPI 0: bf16 out; 2: +resid bf16; 3: dual K/V out, V transposed into C2
template <int EPI, int SWZ>
__global__ __launch_bounds__(256, 2) void gemm128(const u16* __restrict__ A,
                                                  const u16* __restrict__ W,
                                                  const float* __restrict__ bias,
                                                  u16* __restrict__ C,
                                                  const u16* __restrict__ resid,
                                                  u16* __restrict__ C2,
                                                  const float* __restrict__ bias2,
                                                  int K) {
  __shared__ u16 As[2][128 * 32];
  __shared__ u16 Bs[2][128 * 32];
  const int tid = threadIdx.x;
  const int wave = tid >> 6, lane = tid & 63;
  const int wm = (wave & 1) * 64, wn = (wave >> 1) * 64;
  const int quad = lane >> 4, l16 = lane & 15;
  int m_t, n_t;
  if (SWZ) {  // bid&7 = XCD slot; N-blocks sharing an A-tile on one XCD
    const int bid = blockIdx.x;
    const int xcd = bid & 7, j = bid >> 3;
    n_t = j & 3;
    m_t = xcd + (j >> 2) * 8;
  } else {
    m_t = blockIdx.x; n_t = blockIdx.y;
  }
  const int m0 = m_t * 128, n0 = n_t * 128;

  f32x4 acc[4][4];
#pragma unroll
  for (int i = 0; i < 4; ++i)
#pragma unroll
    for (int j = 0; j < 4; ++j) acc[i][j] = f32x4{0.f, 0.f, 0.f, 0.f};

  const int srow = wave * 32 + (lane >> 2);
  const int scol = (lane & 3) * 8;
  const u16* gA0 = A + (size_t)(m0 + srow) * K + scol;
  const u16* gA1 = gA0 + (size_t)16 * K;
  const u16* gW0 = W + (size_t)(n0 + srow) * K + scol;
  const u16* gW1 = gW0 + (size_t)16 * K;
  const int wb = wave * 1024;

  // prologue: fill buffer 0
  gl_lds16(gA0, &As[0][wb]);
  gl_lds16(gA1, &As[0][wb + 512]);
  gl_lds16(gW0, &Bs[0][wb]);
  gl_lds16(gW1, &Bs[0][wb + 512]);

  int buf = 0;
  for (int k0 = 0; k0 < K; k0 += 32, buf ^= 1) {
    __syncthreads();  // vmcnt drain: buf ready; prior reads of buf^1 done
    if (k0 + 32 < K) {
      const int nb = buf ^ 1, k1 = k0 + 32;
      gl_lds16(gA0 + k1, &As[nb][wb]);
      gl_lds16(gA1 + k1, &As[nb][wb + 512]);
      gl_lds16(gW0 + k1, &Bs[nb][wb]);
      gl_lds16(gW1 + k1, &Bs[nb][wb + 512]);
    }
    s16x8 af[4], bfr[4];
#pragma unroll
    for (int mt = 0; mt < 4; ++mt)
      af[mt] = *(const s16x8*)&As[buf][(wm + mt * 16 + l16) * 32 + quad * 8];
#pragma unroll
    for (int nt = 0; nt < 4; ++nt)
      bfr[nt] = *(const s16x8*)&Bs[buf][(wn + nt * 16 + l16) * 32 + quad * 8];
#pragma unroll
    for (int mt = 0; mt < 4; ++mt)
#pragma unroll
      for (int nt = 0; nt < 4; ++nt)
        acc[mt][nt] = mfma16(af[mt], bfr[nt], acc[mt][nt]);
  }

#pragma unroll
  for (int nt = 0; nt < 4; ++nt) {
    const int n = n0 + wn + nt * 16 + l16;
    const float bia = (EPI == 3) ? (n < BD ? bias[n] : bias2[n - BD]) : bias[n];
#pragma unroll
    for (int mt = 0; mt < 4; ++mt) {
      const int mb = m0 + wm + mt * 16 + quad * 4;
      if (EPI == 3 && n >= BD) {
        u16x4 pk;  // V out transposed: VT[b][n-512][k], b=m>>8, k=m&255
#pragma unroll
        for (int r = 0; r < 4; ++r) pk[r] = f2bf(acc[mt][nt][r] + bia);
        const int b = mb >> 8, k0i = mb & 255;
        *(u16x4*)&C2[((size_t)b * BD + (n - BD)) * LYK + k0i] = pk;
      } else {
#pragma unroll
        for (int r = 0; r < 4; ++r) {
          float v = acc[mt][nt][r] + bia;
          size_t idx = (size_t)(mb + r) * BD + n;
          if (EPI == 2) v += bf2f(resid[idx]);
          C[idx] = f2bf(v);
        }
      }
    }
  }
}

// ---------------- attention: per (qtile64, head, batch) -------------------
// S^T = K*Q^T trick: each lane's scores all belong to query l16 -> softmax
// is in-lane + 2 shuffles, P write-back is b64-vectorized. Both K and VT
// staged in LDS (coalesced b128); P overlays the K region after one barrier.
__global__ __launch_bounds__(256, 2) void attn_k(const u16* __restrict__ Q,
                                                 const u16* __restrict__ Kg,
                                                 const u16* __restrict__ VT,
                                                 const int* __restrict__ off,
                                                 u16* __restrict__ O) {
  const int t = blockIdx.x, h = blockIdx.y, b = blockIdx.z;
  const int qend = off[b + 1];
  const int qstart = off[b] + t * 64;
  if (qstart >= qend) return;

  __shared__ u16 KT[256 * 72];   // K [key][d], stride 72; later P[64][264]
  __shared__ u16 VTs[64 * 264];  // V^T [d][key], stride 264

  const int tid = threadIdx.x;
  const int wave = tid >> 6, lane = tid & 63;
  const int quad = lane >> 4, l16 = lane & 15;

  {  // stage K_h [256][64] (coalesced 16B chunks)
    const u16* src = Kg + (size_t)b * LYK * BD + h * 64;
#pragma unroll
    for (int s = 0; s < 8; ++s) {
      int c = tid + s * 256;
      int r = c >> 3, col = (c & 7) * 8;
      *(s16x8*)&KT[r * 72 + col] = *(const s16x8*)&src[(size_t)r * BD + col];
    }
  }
  {  // stage V^T slice [64][256] (rows contiguous in global)
    const u16* src = VT + ((size_t)b * BD + h * 64) * LYK;
#pragma unroll
    for (int s = 0; s < 8; ++s) {
      int c = tid + s * 256;
      int r = c >> 5, col = (c & 31) * 8;
      *(s16x8*)&VTs[r * 264 + col] = *(const s16x8*)&src[(size_t)r * LYK + col];
    }
  }
  // Q fragments (B-operand; n=l16 -> query)
  int qrow = qstart + wave * 16 + l16;
  if (qrow > NTOK - 1) qrow = NTOK - 1;
  const u16* qp = Q + (size_t)qrow * BD + h * 64 + quad * 8;
  s16x8 aq0 = *(const s16x8*)qp;
  s16x8 aq1 = *(const s16x8*)(qp + 32);

  __syncthreads();

  // S^T = K Q^T : D[m=key][n=query]; lane holds keys nt*16+quad*4+r, query l16
  f32x4 sacc[16];
#pragma unroll
  for (int nt = 0; nt < 16; ++nt) sacc[nt] = f32x4{0.f, 0.f, 0.f, 0.f};
#pragma unroll
  for (int nt = 0; nt < 16; ++nt) {
    const u16* kp = &KT[(nt * 16 + l16) * 72 + quad * 8];
    s16x8 k0 = *(const s16x8*)kp;
    s16x8 k1 = *(const s16x8*)(kp + 32);
    sacc[nt] = mfma16(k0, aq0, sacc[nt]);
    sacc[nt] = mfma16(k1, aq1, sacc[nt]);
  }

  // softmax for query l16: in-lane reduce over 64 vals + 2 quad-shuffles
  float mx = -1e30f;
#pragma unroll
  for (int nt = 0; nt < 16; ++nt)
#pragma unroll
    for (int r = 0; r < 4; ++r) mx = fmaxf(mx, sacc[nt][r]);
  mx = fmaxf(mx, __shfl_xor(mx, 16));
  mx = fmaxf(mx, __shfl_xor(mx, 32));
  float sum = 0.f;
#pragma unroll
  for (int nt = 0; nt < 16; ++nt)
#pragma unroll
    for (int r = 0; r < 4; ++r) {
      float p = __expf(0.125f * (sacc[nt][r] - mx));
      sacc[nt][r] = p;
      sum += p;
    }
  sum += __shfl_xor(sum, 16);
  sum += __shfl_xor(sum, 32);
  const float inv = 1.f / sum;

  __syncthreads();  // all waves done reading KT before P overlays it

  // P[query][key], stride 264, normalized bf16; b64 writes (4 keys/lane)
  u16* P = KT;
  const int prow = (wave * 16 + l16) * 264;
#pragma unroll
  for (int nt = 0; nt < 16; ++nt) {
    u16x4 pk;
#pragma unroll
    for (int r = 0; r < 4; ++r) pk[r] = f2bf_fast(sacc[nt][r] * inv);
    *(u16x4*)&P[prow + nt * 16 + quad * 4] = pk;
  }

  // O = P V : A-frags from own wave's P rows (no barrier needed), B from VTs
  f32x4 oacc[4];
#pragma unroll
  for (int n2 = 0; n2 < 4; ++n2) oacc[n2] = f32x4{0.f, 0.f, 0.f, 0.f};
#pragma unroll
  for (int kc = 0; kc < 8; ++kc) {
    s16x8 ap = *(const s16x8*)&P[prow + kc * 32 + quad * 8];
#pragma unroll
    for (int n2 = 0; n2 < 4; ++n2) {
      s16x8 bv = *(const s16x8*)&VTs[(n2 * 16 + l16) * 264 + kc * 32 + quad * 8];
      oacc[n2] = mfma16(ap, bv, oacc[n2]);
    }
  }

#pragma unroll
  for (int n2 = 0; n2 < 4; ++n2)
#pragma unroll
    for (int r = 0; r < 4; ++r) {
      int q = qstart + wave * 16 + quad * 4 + r;
      if (q < qend)
        O[(size_t)q * BD + h * 64 + n2 * 16 + l16] = f2bf(oacc[n2][r]);
    }
}

extern "C" void kernel_launch(void* const* d_in, const int* in_sizes, int n_in,
                              void* d_out, int out_size, void* d_ws, size_t ws_size,
                              hipStream_t stream) {
  const float* F    = (const float*)d_in[0];
  const float* yIn  = (const float*)d_in[1];
  const float* ln_g = (const float*)d_in[2];
  const float* ln_b = (const float*)d_in[3];
  const float* Wq   = (const float*)d_in[4];
  const float* Wk   = (const float*)d_in[5];
  const float* Wv   = (const float*)d_in[6];
  const float* bq   = (const float*)d_in[7];
  const float* bk   = (const float*)d_in[8];
  const float* bv   = (const float*)d_in[9];
  const float* Wo   = (const float*)d_in[10];
  const float* bo   = (const float*)d_in[11];
  const float* W1   = (const float*)d_in[12];
  const float* b1   = (const float*)d_in[13];
  const float* W2   = (const float*)d_in[14];
  const float* b2   = (const float*)d_in[15];
  const int* bids   = (const int*)d_in[16];

  char* ws = (char*)d_ws;
  size_t cur = 0;
  auto alloc = [&](size_t bytes) {
    void* p = ws + cur;
    cur += (bytes + 255) & ~(size_t)255;
    return p;
  };

  int* off   = (int*)alloc(68);
  u16* wq_b  = (u16*)alloc((size_t)262144 * 2);
  u16* wkv_b = (u16*)alloc((size_t)524288 * 2);   // [Wk; Wv] stacked, 1024x512
  u16* wo_b  = (u16*)alloc((size_t)262144 * 2);
  u16* w2_b  = (u16*)alloc((size_t)262144 * 2);
  u16* w1_b  = (u16*)alloc((size_t)393216 * 2);
  u16* y_b   = (u16*)alloc((size_t)3145728 * 2);
  u16* U     = (u16*)alloc((size_t)4096 * BD * 2);
  u16* ym    = (u16*)alloc((size_t)4096 * BD * 2);
  u16* Kb    = (u16*)alloc((size_t)4096 * BD * 2);
  u16* VT    = (u16*)alloc((size_t)NB * BD * LYK * 2);  // [b][dh_full][key]
  u16* xn    = (u16*)alloc((size_t)NTOK * BD * 2);
  u16* Qb    = (u16*)alloc((size_t)NTOK * BD * 2);
  u16* Ob    = (u16*)alloc((size_t)NTOK * BD * 2);
  u16* Zb    = (u16*)alloc((size_t)NTOK * BD * 2);

  prep<<<10561, 256, 0, stream>>>(Wq, Wk, Wv, Wo, W2, W1, yIn, F, ln_g, ln_b, bids,
                                  wq_b, wkv_b, wo_b, w2_b, w1_b, y_b, xn, off);

  // image-feature MLP (M = 4096)
  gemm64<1><<<dim3(64, 4), 256, 0, stream>>>(y_b, w1_b, b1, U, IMGD);
  gemm64<0><<<dim3(64, 4), 256, 0, stream>>>(U, w2_b, b2, ym, BD);
  // fused K/V projection, N=1024; V written transposed into VT
  gemm128<3, 0><<<dim3(32, 8), 256, 0, stream>>>(ym, wkv_b, bk, Kb, nullptr, VT, bv, BD);
  // Q projection (M = 32768), XCD-swizzled 1-D grid
  gemm128<0, 1><<<1024, 256, 0, stream>>>(xn, wq_b, bq, Qb, nullptr, nullptr, nullptr, BD);
  // cross-attention on real tokens only
  attn_k<<<dim3(36, 8, NB), 256, 0, stream>>>(Qb, Kb, VT, off, Ob);
  // output projection + residual, XCD-swizzled
  gemm128<2, 1><<<1024, 256, 0, stream>>>(Ob, wo_b, bo, Zb, xn, nullptr, nullptr, BD);
  ln_bf16_f32<<<NTOK / 4, 256, 0, stream>>>(Zb, ln_g, ln_b, (float*)d_out);
}